// Round 13
// baseline (193.276 us; speedup 1.0000x reference)
//
#include <hip/hip_runtime.h>
#include <cstdint>
#include <cstddef>

// Problem constants (N=2, C=128, Ce=64, H=W=96)
#define HW_ 9216
#define CC 128
#define NQT 144      // HW/64 p-tiles (conv)
#define NQT2 72      // HW/128 q-tiles (attn: 128 q per block)
#define LOG2E 1.44269504088896f

typedef short bf16x8 __attribute__((ext_vector_type(8)));
typedef unsigned short u16x4 __attribute__((ext_vector_type(4)));
typedef unsigned short u16x8 __attribute__((ext_vector_type(8)));
typedef float f32x4 __attribute__((ext_vector_type(4)));

__device__ __forceinline__ unsigned short f2bf(float f) {
    unsigned int u = __builtin_bit_cast(unsigned int, f);
    u += 0x7FFFu + ((u >> 16) & 1u);   // RNE
    return (unsigned short)(u >> 16);
}

__device__ __forceinline__ float fast_exp2(float x) {
#if __has_builtin(__builtin_amdgcn_exp2f)
    return __builtin_amdgcn_exp2f(x);   // bare v_exp_f32
#else
    return exp2f(x);
#endif
}

__device__ __forceinline__ unsigned int cvt_pk_bf16(float lo, float hi) {
    unsigned int r;
    asm("v_cvt_pk_bf16_f32 %0, %1, %2" : "=v"(r) : "v"(lo), "v"(hi));
    return r;
}

// ---------------------------------------------------------------------------
// Kernel 1: transpose weights into wt[c][o], o in [0,256): 0..63=w1, 64..127=w2,
// 128..255=wa.
// ---------------------------------------------------------------------------
__global__ __launch_bounds__(256) void prep_w(const float* __restrict__ w1,
                                              const float* __restrict__ w2,
                                              const float* __restrict__ wa,
                                              float* __restrict__ wt) {
    int idx = blockIdx.x * 256 + threadIdx.x;   // 32768 total
    int o = idx >> 7, c = idx & 127;
    float v;
    if (o < 64)       v = w1[o * 128 + c];
    else if (o < 128) v = w2[(o - 64) * 128 + c];
    else              v = wa[(o - 128) * 128 + c];
    wt[c * 256 + o] = v;
}

// ---------------------------------------------------------------------------
// Kernel 2: 1x1 conv + PReLU (fp32 accumulate), write bf16.
//   oset 0 -> Q[n][p][d] (pre-scaled by log2e), 1 -> K, 2,3 -> Vt[c][p].
// R13: pure-DS inner loop. R12 post-mortem: mixing s_load (wt) with ds_read
// (xs) forces lgkmcnt(0) full drains every c (SMEM returns out-of-order ->
// conservative waits), re-exposing ~200cy latency 128x. Fix: stage the wt
// slice in LDS too (c split into two 64-row passes; xs 16KB + ws 16KB =
// 32KB). Pure-DS is in-order -> counted lgkmcnt -> pipelined.
// Values bit-identical to R12 (same fp32 FMA order).
// ---------------------------------------------------------------------------
__global__ __launch_bounds__(256) void conv_kernel(
    const float* __restrict__ x, const float* __restrict__ wt,
    const float* __restrict__ b1, const float* __restrict__ a1,
    const float* __restrict__ b2, const float* __restrict__ a2,
    const float* __restrict__ ba, const float* __restrict__ aa,
    unsigned short* __restrict__ qb, unsigned short* __restrict__ kb,
    unsigned short* __restrict__ vtb) {
    const int ptile = blockIdx.x;   // 144
    const int oset  = blockIdx.y;   // 4
    const int n     = blockIdx.z;   // 2
    const int t = threadIdx.x;
    const int p = t & 63;
    const int og = __builtin_amdgcn_readfirstlane(t >> 6);
    const int p0 = ptile * 64;

    __shared__ float xs[64 * 64];   // x[c0+cc][p] slice, 16 KB
    __shared__ float ws[64 * 64];   // wt[c0+cc][oset*64+ol] slice, 16 KB

    float acc[16];
#pragma unroll
    for (int i = 0; i < 16; i++) acc[i] = 0.f;

    const int obl = og * 16;        // wave's o_local base within the oset

    for (int half = 0; half < 2; half++) {
        const int c0 = half * 64;
        __syncthreads();   // previous pass's reads complete before overwrite
        {   // float4 staging: thread t covers rows cc = t>>4 step 16, 4 cols
            const int cs = t >> 4, q4 = (t & 15) * 4;
#pragma unroll
            for (int cc = cs; cc < 64; cc += 16) {
                float4 xv = *(const float4*)(x + ((size_t)n * CC + c0 + cc) * HW_ + p0 + q4);
                *(float4*)&xs[cc * 64 + q4] = xv;
                float4 wv = *(const float4*)(wt + (size_t)(c0 + cc) * 256 + oset * 64 + q4);
                *(float4*)&ws[cc * 64 + q4] = wv;
            }
        }
        __syncthreads();

#pragma unroll 8
        for (int cc = 0; cc < 64; cc++) {
            float xv = xs[cc * 64 + p];
            float4 w0 = *(const float4*)&ws[cc * 64 + obl + 0];   // uniform -> broadcast
            float4 w1 = *(const float4*)&ws[cc * 64 + obl + 4];
            float4 w2v = *(const float4*)&ws[cc * 64 + obl + 8];
            float4 w3 = *(const float4*)&ws[cc * 64 + obl + 12];
            acc[0]  = fmaf(w0.x, xv, acc[0]);
            acc[1]  = fmaf(w0.y, xv, acc[1]);
            acc[2]  = fmaf(w0.z, xv, acc[2]);
            acc[3]  = fmaf(w0.w, xv, acc[3]);
            acc[4]  = fmaf(w1.x, xv, acc[4]);
            acc[5]  = fmaf(w1.y, xv, acc[5]);
            acc[6]  = fmaf(w1.z, xv, acc[6]);
            acc[7]  = fmaf(w1.w, xv, acc[7]);
            acc[8]  = fmaf(w2v.x, xv, acc[8]);
            acc[9]  = fmaf(w2v.y, xv, acc[9]);
            acc[10] = fmaf(w2v.z, xv, acc[10]);
            acc[11] = fmaf(w2v.w, xv, acc[11]);
            acc[12] = fmaf(w3.x, xv, acc[12]);
            acc[13] = fmaf(w3.y, xv, acc[13]);
            acc[14] = fmaf(w3.z, xv, acc[14]);
            acc[15] = fmaf(w3.w, xv, acc[15]);
        }
    }

    const int obase = oset * 64 + obl;
    const float* bias_p;
    const float* slope_p;
    if (oset == 0)      { bias_p = b1; slope_p = a1; }
    else if (oset == 1) { bias_p = b2; slope_p = a2; }
    else                { bias_p = ba; slope_p = aa; }
    const float slope = slope_p[0];

    unsigned short vals[16];
#pragma unroll
    for (int i = 0; i < 16; i++) {
        float bv = (oset < 2) ? bias_p[obl + i] : bias_p[obase - 128 + i];
        float y = acc[i] + bv;
        y = (y >= 0.f) ? y : slope * y;
        if (oset == 0) y *= LOG2E;   // fold softmax's ln->log2 into Q
        vals[i] = f2bf(y);
    }

    if (oset < 2) {
        unsigned short* dst = (oset == 0 ? qb : kb) + ((size_t)n * HW_ + p0 + p) * 64 + obl;
        bf16x8 v0, v1;
#pragma unroll
        for (int i = 0; i < 8; i++) { v0[i] = (short)vals[i]; v1[i] = (short)vals[8 + i]; }
        *(bf16x8*)(dst)     = v0;
        *(bf16x8*)(dst + 8) = v1;
    } else {
        int c0 = obase - 128;
#pragma unroll
        for (int i = 0; i < 16; i++)
            vtb[((size_t)n * CC + c0 + i) * HW_ + p0 + p] = vals[i];
    }
}

// ---------------------------------------------------------------------------
// Kernel 3: flash attention, S^T formulation, 32 q per wave, NO-MAX softmax.
//   EXACT R6 kernel (proven 94-96 us attn, best of 7 structural variants).
//   S^T = K·Q^T  (A=K, B=Q)  -> C/D: col = q = lane&15, row = j = quad*4+r
//   P = exp2(S) raw (softmax shift-invariance; S bounded ~40 in log2 domain)
//   l accumulates in-lane; one 2-shfl reduce at epilogue; combine = plain sums
//   P^T staged per-wave in a 1KB buffer reused by both halves (write-a,
//   read-a, write-b, read-b; per-wave DS ops in-order; fences pin order).
//   O^T = V^T·P^T (A=V^T, B=P^T) -> col = q, row = c-local
// Block = 4 waves x 32 q = 128 q. KV chunked over blockIdx.y.
// ---------------------------------------------------------------------------
__global__ __launch_bounds__(256, 2) void attn_kernel(
    const unsigned short* __restrict__ qb, const unsigned short* __restrict__ kb,
    const unsigned short* __restrict__ vtb,
    float* __restrict__ o_part, float* __restrict__ l_part,
    int nch, int chunk_j) {
    const int qt    = blockIdx.x;   // 72
    const int chunk = blockIdx.y;   // nch
    const int n     = blockIdx.z;   // 2
    const int t = threadIdx.x;
    const int w = t >> 6;
    const int lane = t & 63;
    const int l15 = lane & 15;
    const int quad = lane >> 4;
    const int e7 = l15 & 7;

    __shared__ __align__(16) unsigned short k_lds[64 * 64];   // [j][d] swizzled, 8 KB
    __shared__ __align__(16) unsigned short v_lds[128 * 64];  // [c][j] swizzled, 16 KB
    __shared__ __align__(16) unsigned short p_lds[4 * 1024];  // per-wave [q][j], 8 KB

    // Q B-fragments for the two 16-q halves: lane holds q=l15, d = quad*8..
    const int row_ga = qt * 128 + w * 32 + l15;
    const int row_gb = row_ga + 16;
    const bf16x8 bq0a = *(const bf16x8*)(qb + ((size_t)n * HW_ + row_ga) * 64 + quad * 8);
    const bf16x8 bq1a = *(const bf16x8*)(qb + ((size_t)n * HW_ + row_ga) * 64 + 32 + quad * 8);
    const bf16x8 bq0b = *(const bf16x8*)(qb + ((size_t)n * HW_ + row_gb) * 64 + quad * 8);
    const bf16x8 bq1b = *(const bf16x8*)(qb + ((size_t)n * HW_ + row_gb) * 64 + 32 + quad * 8);

    f32x4 acc_oa[8], acc_ob[8];
#pragma unroll
    for (int i = 0; i < 8; i++) {
        acc_oa[i] = (f32x4){0.f, 0.f, 0.f, 0.f};
        acc_ob[i] = (f32x4){0.f, 0.f, 0.f, 0.f};
    }
    float l_sa = 0.f, l_sb = 0.f;   // in-lane partial of l(q); reduced at end

    const int stg_row = t >> 3, stg_seg = t & 7;
    const int iters = chunk_j / 64;
    int j0 = chunk * chunk_j;

    // software pipeline: prefetch tile 0 into VGPRs
    bf16x8 kr0, kr1, vr0, vr1, vr2, vr3;
    {
        const unsigned short* kp = kb + ((size_t)n * HW_ + j0 + stg_row) * 64 + stg_seg * 8;
        kr0 = *(const bf16x8*)kp;
        kr1 = *(const bf16x8*)(kp + 32 * 64);
        const unsigned short* vp = vtb + ((size_t)n * CC + stg_row) * HW_ + j0 + stg_seg * 8;
        vr0 = *(const bf16x8*)vp;
        vr1 = *(const bf16x8*)(vp + (size_t)32 * HW_);
        vr2 = *(const bf16x8*)(vp + (size_t)64 * HW_);
        vr3 = *(const bf16x8*)(vp + (size_t)96 * HW_);
    }

    for (int it = 0; it < iters; ++it, j0 += 64) {
        __syncthreads();   // previous iteration's k/v_lds reads complete
        {
            int r0 = stg_row, r1 = stg_row + 32;
            *(bf16x8*)&k_lds[r0 * 64 + ((stg_seg ^ (r0 & 7)) * 8)] = kr0;
            *(bf16x8*)&k_lds[r1 * 64 + ((stg_seg ^ (r1 & 7)) * 8)] = kr1;
            *(bf16x8*)&v_lds[r0 * 64 + ((stg_seg ^ (r0 & 7)) * 8)] = vr0;
            *(bf16x8*)&v_lds[r1 * 64 + ((stg_seg ^ (r1 & 7)) * 8)] = vr1;
            int r2 = stg_row + 64, r3 = stg_row + 96;
            *(bf16x8*)&v_lds[r2 * 64 + ((stg_seg ^ (r2 & 7)) * 8)] = vr2;
            *(bf16x8*)&v_lds[r3 * 64 + ((stg_seg ^ (r3 & 7)) * 8)] = vr3;
        }
        __syncthreads();

        if (it + 1 < iters) {   // issue next tile's loads; overlap with compute
            const unsigned short* kp = kb + ((size_t)n * HW_ + j0 + 64 + stg_row) * 64 + stg_seg * 8;
            kr0 = *(const bf16x8*)kp;
            kr1 = *(const bf16x8*)(kp + 32 * 64);
            const unsigned short* vp = vtb + ((size_t)n * CC + stg_row) * HW_ + j0 + 64 + stg_seg * 8;
            vr0 = *(const bf16x8*)vp;
            vr1 = *(const bf16x8*)(vp + (size_t)32 * HW_);
            vr2 = *(const bf16x8*)(vp + (size_t)64 * HW_);
            vr3 = *(const bf16x8*)(vp + (size_t)96 * HW_);
        }

        // S^T = K Q^T: 4 tiles along j (16 each), both q-halves per A-read
        f32x4 sa[4], sb[4];
#pragma unroll
        for (int ct = 0; ct < 4; ct++) {
            int jr = ct * 16 + l15;
            bf16x8 ak0 = *(const bf16x8*)&k_lds[jr * 64 + ((quad ^ e7) * 8)];
            bf16x8 ak1 = *(const bf16x8*)&k_lds[jr * 64 + (((4 + quad) ^ e7) * 8)];
            f32x4 za = (f32x4){0.f, 0.f, 0.f, 0.f};
            za = __builtin_amdgcn_mfma_f32_16x16x32_bf16(ak0, bq0a, za, 0, 0, 0);
            za = __builtin_amdgcn_mfma_f32_16x16x32_bf16(ak1, bq1a, za, 0, 0, 0);
            sa[ct] = za;
            f32x4 zb = (f32x4){0.f, 0.f, 0.f, 0.f};
            zb = __builtin_amdgcn_mfma_f32_16x16x32_bf16(ak0, bq0b, zb, 0, 0, 0);
            zb = __builtin_amdgcn_mfma_f32_16x16x32_bf16(ak1, bq1b, zb, 0, 0, 0);
            sb[ct] = zb;
        }

        // ---- half a: P = exp2(S) raw (no max), in-lane l, pack, stage ----
#pragma unroll
        for (int ct = 0; ct < 4; ct++) {
            sa[ct][0] = fast_exp2(sa[ct][0]);
            sa[ct][1] = fast_exp2(sa[ct][1]);
            sa[ct][2] = fast_exp2(sa[ct][2]);
            sa[ct][3] = fast_exp2(sa[ct][3]);
        }
        {   // explicit pairwise tree (no fast-math reassociation available)
            float u0 = sa[0][0] + sa[0][1], u1 = sa[0][2] + sa[0][3];
            float u2 = sa[1][0] + sa[1][1], u3 = sa[1][2] + sa[1][3];
            float u4 = sa[2][0] + sa[2][1], u5 = sa[2][2] + sa[2][3];
            float u6 = sa[3][0] + sa[3][1], u7 = sa[3][2] + sa[3][3];
            float v0 = u0 + u1, v1 = u2 + u3, v2 = u4 + u5, v3 = u6 + u7;
            l_sa += (v0 + v1) + (v2 + v3);
        }
#pragma unroll
        for (int ct = 0; ct < 4; ct++) {
            unsigned int pk01 = cvt_pk_bf16(sa[ct][0], sa[ct][1]);
            unsigned int pk23 = cvt_pk_bf16(sa[ct][2], sa[ct][3]);
            int chunkid = 2 * ct + (quad >> 1);
            int off = l15 * 64 + ((chunkid ^ e7) * 8) + 4 * (quad & 1);
            uint2 tmp;
            tmp.x = pk01;
            tmp.y = pk23;
            *(u16x4*)&p_lds[w * 1024 + off] = __builtin_bit_cast(u16x4, tmp);
        }
        asm volatile("" ::: "memory");   // writes-a before reads-a
        const bf16x8 bp0a = __builtin_bit_cast(bf16x8,
            *(const u16x8*)&p_lds[w * 1024 + l15 * 64 + ((quad ^ e7) * 8)]);
        const bf16x8 bp1a = __builtin_bit_cast(bf16x8,
            *(const u16x8*)&p_lds[w * 1024 + l15 * 64 + (((4 + quad) ^ e7) * 8)]);
        asm volatile("" ::: "memory");   // reads-a before writes-b (buffer reuse)

        // ---- half b ----
#pragma unroll
        for (int ct = 0; ct < 4; ct++) {
            sb[ct][0] = fast_exp2(sb[ct][0]);
            sb[ct][1] = fast_exp2(sb[ct][1]);
            sb[ct][2] = fast_exp2(sb[ct][2]);
            sb[ct][3] = fast_exp2(sb[ct][3]);
        }
        {
            float u0 = sb[0][0] + sb[0][1], u1 = sb[0][2] + sb[0][3];
            float u2 = sb[1][0] + sb[1][1], u3 = sb[1][2] + sb[1][3];
            float u4 = sb[2][0] + sb[2][1], u5 = sb[2][2] + sb[2][3];
            float u6 = sb[3][0] + sb[3][1], u7 = sb[3][2] + sb[3][3];
            float v0 = u0 + u1, v1 = u2 + u3, v2 = u4 + u5, v3 = u6 + u7;
            l_sb += (v0 + v1) + (v2 + v3);
        }
#pragma unroll
        for (int ct = 0; ct < 4; ct++) {
            unsigned int pk01 = cvt_pk_bf16(sb[ct][0], sb[ct][1]);
            unsigned int pk23 = cvt_pk_bf16(sb[ct][2], sb[ct][3]);
            int chunkid = 2 * ct + (quad >> 1);
            int off = l15 * 64 + ((chunkid ^ e7) * 8) + 4 * (quad & 1);
            uint2 tmp;
            tmp.x = pk01;
            tmp.y = pk23;
            *(u16x4*)&p_lds[w * 1024 + off] = __builtin_bit_cast(u16x4, tmp);
        }
        asm volatile("" ::: "memory");   // writes-b before reads-b
        const bf16x8 bp0b = __builtin_bit_cast(bf16x8,
            *(const u16x8*)&p_lds[w * 1024 + l15 * 64 + ((quad ^ e7) * 8)]);
        const bf16x8 bp1b = __builtin_bit_cast(bf16x8,
            *(const u16x8*)&p_lds[w * 1024 + l15 * 64 + (((4 + quad) ^ e7) * 8)]);
        asm volatile("" ::: "memory");   // reads-b before next iter's writes-a

        // O^T += V^T P^T (both halves share each V A-read)
        __builtin_amdgcn_s_setprio(1);
#pragma unroll
        for (int ctv = 0; ctv < 8; ctv++) {
            int cr = ctv * 16 + l15;
            bf16x8 av0 = *(const bf16x8*)&v_lds[cr * 64 + ((quad ^ e7) * 8)];
            bf16x8 av1 = *(const bf16x8*)&v_lds[cr * 64 + (((4 + quad) ^ e7) * 8)];
            acc_oa[ctv] = __builtin_amdgcn_mfma_f32_16x16x32_bf16(av0, bp0a, acc_oa[ctv], 0, 0, 0);
            acc_oa[ctv] = __builtin_amdgcn_mfma_f32_16x16x32_bf16(av1, bp1a, acc_oa[ctv], 0, 0, 0);
            acc_ob[ctv] = __builtin_amdgcn_mfma_f32_16x16x32_bf16(av0, bp0b, acc_ob[ctv], 0, 0, 0);
            acc_ob[ctv] = __builtin_amdgcn_mfma_f32_16x16x32_bf16(av1, bp1b, acc_ob[ctv], 0, 0, 0);
        }
        __builtin_amdgcn_s_setprio(0);
    }

    // epilogue: reduce l across quads (once per kernel, not per iter)
    l_sa += __shfl_xor(l_sa, 16);
    l_sa += __shfl_xor(l_sa, 32);
    l_sb += __shfl_xor(l_sb, 16);
    l_sb += __shfl_xor(l_sb, 32);

    // partials: O^T layout [c][q], q in [0,128) per block
    const size_t cbase = ((size_t)(n * NQT2 + qt) * nch + chunk) * 128;
    const int qla = w * 32 + l15, qlb = qla + 16;
#pragma unroll
    for (int ctv = 0; ctv < 8; ctv++)
#pragma unroll
        for (int r = 0; r < 4; r++) {
            int c = ctv * 16 + 4 * quad + r;
            o_part[(cbase + c) * 128 + qla] = acc_oa[ctv][r];
            o_part[(cbase + c) * 128 + qlb] = acc_ob[ctv][r];
        }
    if (quad == 0) {   // l is quad-uniform per q after the reduce
        size_t lb = ((size_t)(n * NQT2 + qt) * nch + chunk) * 128;
        l_part[lb + qla] = l_sa;
        l_part[lb + qlb] = l_sb;
    }
}

// ---------------------------------------------------------------------------
// Kernel 4: combine nch partials (plain sums — no max tracking), normalize,
// write out[n][c][p] fp32. float4-vectorized over q (4 q per thread).
// Layout: o_part[((nqt*nch+ch)*128 + c)*128 + q], l[(nqt*nch+ch)*128 + q]
// ---------------------------------------------------------------------------
__global__ __launch_bounds__(256) void combine_kernel(
    const float* __restrict__ o_part, const float* __restrict__ lp,
    float* __restrict__ out, int nch) {
    int gid = blockIdx.x * 256 + threadIdx.x;   // covers (nqt, c, q/4)
    int r4 = (gid & 31) * 4;       // q within block, 4 at a time
    int rest = gid >> 5;
    int c = rest & 127;
    int nqt = rest >> 7;           // 0..143 = n*72 + qtp
    int n = nqt / NQT2, qtp = nqt - n * NQT2;

    float4 num = {0.f, 0.f, 0.f, 0.f}, den = {0.f, 0.f, 0.f, 0.f};
    for (int ch = 0; ch < nch; ch++) {
        float4 o = *(const float4*)&o_part[(((size_t)nqt * nch + ch) * 128 + c) * 128 + r4];
        float4 l = *(const float4*)&lp[((size_t)nqt * nch + ch) * 128 + r4];
        num.x += o.x; num.y += o.y; num.z += o.z; num.w += o.w;
        den.x += l.x; den.y += l.y; den.z += l.z; den.w += l.w;
    }
    float4 res;
    res.x = num.x / den.x;
    res.y = num.y / den.y;
    res.z = num.z / den.z;
    res.w = num.w / den.w;
    *(float4*)&out[((size_t)n * CC + c) * HW_ + qtp * 128 + r4] = res;
}

// ---------------------------------------------------------------------------
// Workspace layout (bytes):
//   wt 0 (131072) | qb 131072 (2359296) | kb 2490368 (2359296)
//   vtb 4849664 (4718592) | o_part 9568256 (nch*9437184) | l after o_part
// l = nch * 73728 bytes. Ladder: nch 6 (~67 MB, R6-proven) -> 4 -> 2.
// ---------------------------------------------------------------------------
extern "C" void kernel_launch(void* const* d_in, const int* in_sizes, int n_in,
                              void* d_out, int out_size, void* d_ws, size_t ws_size,
                              hipStream_t stream) {
    const float* x  = (const float*)d_in[0];
    const float* w1 = (const float*)d_in[1];
    const float* b1 = (const float*)d_in[2];
    const float* a1 = (const float*)d_in[3];
    const float* w2 = (const float*)d_in[4];
    const float* b2 = (const float*)d_in[5];
    const float* a2 = (const float*)d_in[6];
    const float* wa = (const float*)d_in[7];
    const float* ba = (const float*)d_in[8];
    const float* aa = (const float*)d_in[9];
    float* out = (float*)d_out;

    auto need = [](int nc) -> size_t {
        return 9568256ull + (size_t)nc * 9437184ull + (size_t)nc * 73728ull;
    };
    int nch;
    if (ws_size >= need(6))      nch = 6;    // R6-proven config
    else if (ws_size >= need(4)) nch = 4;
    else                         nch = 2;
    const int chunk_j = HW_ / nch;

    char* ws = (char*)d_ws;
    float*          wt     = (float*)(ws + 0);
    unsigned short* qb     = (unsigned short*)(ws + 131072);
    unsigned short* kb     = (unsigned short*)(ws + 2490368);
    unsigned short* vtb    = (unsigned short*)(ws + 4849664);
    float*          o_part = (float*)(ws + 9568256);
    float*          lpart  = (float*)(ws + 9568256 + (size_t)nch * 9437184);

    hipLaunchKernelGGL(prep_w, dim3(128), dim3(256), 0, stream, w1, w2, wa, wt);
    hipLaunchKernelGGL(conv_kernel, dim3(144, 4, 2), dim3(256), 0, stream,
                       x, wt, b1, a1, b2, a2, ba, aa, qb, kb, vtb);
    hipLaunchKernelGGL(attn_kernel, dim3(NQT2, nch, 2), dim3(256), 0, stream,
                       qb, kb, vtb, o_part, lpart, nch, chunk_j);
    hipLaunchKernelGGL(combine_kernel, dim3(2 * NQT2 * 128 * 128 / (256 * 4)), dim3(256), 0, stream,
                       o_part, lpart, out, nch);
}

// Round 15
// 183.372 us; speedup vs baseline: 1.0540x; 1.0540x over previous
//
#include <hip/hip_runtime.h>
#include <cstdint>
#include <cstddef>

// Problem constants (N=2, C=128, Ce=64, H=W=96)
#define HW_ 9216
#define CC 128
#define NQT 144      // HW/64 p-tiles (conv)
#define NQT2 72      // HW/128 q-tiles (attn: 128 q per block)
#define LOG2E 1.44269504088896f

typedef short bf16x8 __attribute__((ext_vector_type(8)));
typedef unsigned short u16x4 __attribute__((ext_vector_type(4)));
typedef unsigned short u16x8 __attribute__((ext_vector_type(8)));
typedef float f32x4 __attribute__((ext_vector_type(4)));

__device__ __forceinline__ unsigned short f2bf(float f) {
    unsigned int u = __builtin_bit_cast(unsigned int, f);
    u += 0x7FFFu + ((u >> 16) & 1u);   // RNE
    return (unsigned short)(u >> 16);
}

__device__ __forceinline__ float bf2f(unsigned short h) {
    return __builtin_bit_cast(float, (unsigned int)h << 16);
}

__device__ __forceinline__ float fast_exp2(float x) {
#if __has_builtin(__builtin_amdgcn_exp2f)
    return __builtin_amdgcn_exp2f(x);   // bare v_exp_f32
#else
    return exp2f(x);
#endif
}

__device__ __forceinline__ unsigned int cvt_pk_bf16(float lo, float hi) {
    unsigned int r;
    asm("v_cvt_pk_bf16_f32 %0, %1, %2" : "=v"(r) : "v"(lo), "v"(hi));
    return r;
}

// ---------------------------------------------------------------------------
// Kernel 1: split weights into bf16 hi/lo pairs, [o][c] layout.
//   o in [0,256): 0..63=w1, 64..127=w2, 128..255=wa.
//   w = hi + lo with |lo| <= 2^-9|w|; bf16x3 MFMA then gives ~2^-18 rel error
//   (fp32-equivalent for this problem's tolerances).
// ---------------------------------------------------------------------------
__global__ __launch_bounds__(256) void prep_w(const float* __restrict__ w1,
                                              const float* __restrict__ w2,
                                              const float* __restrict__ wa,
                                              unsigned short* __restrict__ wh,
                                              unsigned short* __restrict__ wl) {
    int idx = blockIdx.x * 256 + threadIdx.x;   // 32768 total
    int o = idx >> 7, c = idx & 127;
    float v;
    if (o < 64)       v = w1[o * 128 + c];
    else if (o < 128) v = w2[(o - 64) * 128 + c];
    else              v = wa[(o - 128) * 128 + c];
    unsigned short h = f2bf(v);
    unsigned short l = f2bf(v - bf2f(h));
    wh[o * 128 + c] = h;
    wl[o * 128 + c] = l;
}

// ---------------------------------------------------------------------------
// Kernel 2: 1x1 conv + PReLU via bf16x3 MFMA (fp32-accurate split GEMM).
//   O(256 o, 64 p per block) = W(256,128) x X(128, p-tile).
//   Block = 4 waves; wave w owns o in [w*64, w*64+64):
//     w0 -> Q (b1,a1, xLOG2E), w1 -> K (b2,a2), w2,w3 -> Vt (ba,aa).
//   X tile staged in LDS as bf16 hi/lo [p][c] (A-frags: row p=l15, k=quad*8).
//   B-frags from wh/wl[o][c] global (L2): lane o=l15, k=quad*8.
//   D: col o = l15, row p = quad*4+r (verified mapping, same as attn).
//   acc = ah*bh + ah*bl + al*bh  (3 MFMA per tile-k: residual ~2^-18).
//   Epilogue: bias+PReLU -> per-wave LDS tile -> vectorized 16B stores.
// Grid 144 x 2 = 288 blocks (~1.1/CU); per-block ~2.5 us critical path.
// ---------------------------------------------------------------------------
__global__ __launch_bounds__(256, 1) void conv_kernel(
    const float* __restrict__ x,
    const unsigned short* __restrict__ wh, const unsigned short* __restrict__ wl,
    const float* __restrict__ b1, const float* __restrict__ a1,
    const float* __restrict__ b2, const float* __restrict__ a2,
    const float* __restrict__ ba, const float* __restrict__ aa,
    unsigned short* __restrict__ qb, unsigned short* __restrict__ kb,
    unsigned short* __restrict__ vtb) {
    const int ptile = blockIdx.x;   // 144
    const int n     = blockIdx.y;   // 2
    const int t = threadIdx.x;
    const int w = t >> 6;           // wave = output group
    const int lane = t & 63;
    const int l15 = lane & 15;
    const int quad = lane >> 4;
    const int p0 = ptile * 64;

    __shared__ __align__(16) unsigned short xh[64 * 136];  // [p][c] pad 8, 17 KB
    __shared__ __align__(16) unsigned short xl[64 * 136];  // 17 KB
    __shared__ __align__(16) unsigned short os[4 * 64 * 72]; // per-wave out tile, 36 KB

    // ---- stage x tile: fp32 -> bf16 hi/lo, transposed to [p][c] ----
    {
        const int cs = t >> 4;          // c start (step 16)
        const int p4 = (t & 15) * 4;    // 4 consecutive p
#pragma unroll
        for (int cc = cs; cc < 128; cc += 16) {
            float4 v = *(const float4*)(x + ((size_t)n * CC + cc) * HW_ + p0 + p4);
            float vv[4] = {v.x, v.y, v.z, v.w};
#pragma unroll
            for (int j = 0; j < 4; j++) {
                unsigned short h = f2bf(vv[j]);
                unsigned short l = f2bf(vv[j] - bf2f(h));
                xh[(p4 + j) * 136 + cc] = h;
                xl[(p4 + j) * 136 + cc] = l;
            }
        }
    }
    __syncthreads();

    // ---- MFMA main loop ----
    f32x4 acc[4][4];   // [ot][pt]
#pragma unroll
    for (int ot = 0; ot < 4; ot++)
#pragma unroll
        for (int pt = 0; pt < 4; pt++) acc[ot][pt] = (f32x4){0.f, 0.f, 0.f, 0.f};

#pragma unroll
    for (int k = 0; k < 4; k++) {          // c_off = k*32
        bf16x8 bh[4], bl[4];
#pragma unroll
        for (int ot = 0; ot < 4; ot++) {
            const size_t woff = (size_t)(w * 64 + ot * 16 + l15) * 128 + k * 32 + quad * 8;
            bh[ot] = *(const bf16x8*)(wh + woff);
            bl[ot] = *(const bf16x8*)(wl + woff);
        }
#pragma unroll
        for (int pt = 0; pt < 4; pt++) {
            const int aoff = (pt * 16 + l15) * 136 + k * 32 + quad * 8;
            bf16x8 ah = *(const bf16x8*)&xh[aoff];
            bf16x8 al = *(const bf16x8*)&xl[aoff];
#pragma unroll
            for (int ot = 0; ot < 4; ot++) {
                acc[ot][pt] = __builtin_amdgcn_mfma_f32_16x16x32_bf16(ah, bh[ot], acc[ot][pt], 0, 0, 0);
                acc[ot][pt] = __builtin_amdgcn_mfma_f32_16x16x32_bf16(ah, bl[ot], acc[ot][pt], 0, 0, 0);
                acc[ot][pt] = __builtin_amdgcn_mfma_f32_16x16x32_bf16(al, bh[ot], acc[ot][pt], 0, 0, 0);
            }
        }
    }

    // ---- epilogue: bias + PReLU (+LOG2E for Q), pack to per-wave LDS tile ----
    const float* bias_p  = (w == 0) ? b1 : (w == 1) ? b2 : ba;
    const float* slope_p = (w == 0) ? a1 : (w == 1) ? a2 : aa;
    const float slope = slope_p[0];
    unsigned short* osw = os + w * 64 * 72;

#pragma unroll
    for (int ot = 0; ot < 4; ot++) {
        const int bidx = (w < 2 ? 0 : (w - 2) * 64) + ot * 16 + l15;
        const float bv = bias_p[bidx];
#pragma unroll
        for (int pt = 0; pt < 4; pt++) {
            unsigned short us[4];
#pragma unroll
            for (int r = 0; r < 4; r++) {
                float y = acc[ot][pt][r] + bv;
                y = (y >= 0.f) ? y : slope * y;
                if (w == 0) y *= LOG2E;   // fold softmax ln->log2 into Q
                us[r] = f2bf(y);
            }
            if (w < 2) {
                // Q/K: [p][o] layout (rows = p for row-major qb/kb stores)
#pragma unroll
                for (int r = 0; r < 4; r++)
                    osw[(pt * 16 + quad * 4 + r) * 72 + ot * 16 + l15] = us[r];
            } else {
                // V: [o][p] layout (rows = c for row-major vtb stores)
                u16x4 pk = {us[0], us[1], us[2], us[3]};
                *(u16x4*)&osw[(ot * 16 + l15) * 72 + pt * 16 + quad * 4] = pk;
            }
        }
    }
    asm volatile("" ::: "memory");   // os writes before same-wave os reads

    // ---- vectorized store: each lane copies one 64-elem row (128 B) ----
    const unsigned short* src = osw + lane * 72;
    unsigned short* dst;
    if (w == 0)      dst = qb + ((size_t)n * HW_ + p0 + lane) * 64;
    else if (w == 1) dst = kb + ((size_t)n * HW_ + p0 + lane) * 64;
    else             dst = vtb + ((size_t)(n * CC + (w - 2) * 64 + lane)) * HW_ + p0;
#pragma unroll
    for (int j = 0; j < 8; j++) {
        u16x8 v = *(const u16x8*)(src + j * 8);
        *(u16x8*)(dst + j * 8) = v;
    }
}

// ---------------------------------------------------------------------------
// Kernel 3: flash attention, S^T formulation, 32 q per wave, NO-MAX softmax.
//   EXACT R6 kernel (proven 94-96 us attn, best of 7 structural variants).
//   S^T = K·Q^T  (A=K, B=Q)  -> C/D: col = q = lane&15, row = j = quad*4+r
//   P = exp2(S) raw (softmax shift-invariance; S bounded ~40 in log2 domain)
//   l accumulates in-lane; one 2-shfl reduce at epilogue; combine = plain sums
//   P^T staged per-wave in a 1KB buffer reused by both halves (write-a,
//   read-a, write-b, read-b; per-wave DS ops in-order; fences pin order).
//   O^T = V^T·P^T (A=V^T, B=P^T) -> col = q, row = c-local
// Block = 4 waves x 32 q = 128 q. KV chunked over blockIdx.y.
// ---------------------------------------------------------------------------
__global__ __launch_bounds__(256, 2) void attn_kernel(
    const unsigned short* __restrict__ qb, const unsigned short* __restrict__ kb,
    const unsigned short* __restrict__ vtb,
    float* __restrict__ o_part, float* __restrict__ l_part,
    int nch, int chunk_j) {
    const int qt    = blockIdx.x;   // 72
    const int chunk = blockIdx.y;   // nch
    const int n     = blockIdx.z;   // 2
    const int t = threadIdx.x;
    const int w = t >> 6;
    const int lane = t & 63;
    const int l15 = lane & 15;
    const int quad = lane >> 4;
    const int e7 = l15 & 7;

    __shared__ __align__(16) unsigned short k_lds[64 * 64];   // [j][d] swizzled, 8 KB
    __shared__ __align__(16) unsigned short v_lds[128 * 64];  // [c][j] swizzled, 16 KB
    __shared__ __align__(16) unsigned short p_lds[4 * 1024];  // per-wave [q][j], 8 KB

    // Q B-fragments for the two 16-q halves: lane holds q=l15, d = quad*8..
    const int row_ga = qt * 128 + w * 32 + l15;
    const int row_gb = row_ga + 16;
    const bf16x8 bq0a = *(const bf16x8*)(qb + ((size_t)n * HW_ + row_ga) * 64 + quad * 8);
    const bf16x8 bq1a = *(const bf16x8*)(qb + ((size_t)n * HW_ + row_ga) * 64 + 32 + quad * 8);
    const bf16x8 bq0b = *(const bf16x8*)(qb + ((size_t)n * HW_ + row_gb) * 64 + quad * 8);
    const bf16x8 bq1b = *(const bf16x8*)(qb + ((size_t)n * HW_ + row_gb) * 64 + 32 + quad * 8);

    f32x4 acc_oa[8], acc_ob[8];
#pragma unroll
    for (int i = 0; i < 8; i++) {
        acc_oa[i] = (f32x4){0.f, 0.f, 0.f, 0.f};
        acc_ob[i] = (f32x4){0.f, 0.f, 0.f, 0.f};
    }
    float l_sa = 0.f, l_sb = 0.f;   // in-lane partial of l(q); reduced at end

    const int stg_row = t >> 3, stg_seg = t & 7;
    const int iters = chunk_j / 64;
    int j0 = chunk * chunk_j;

    // software pipeline: prefetch tile 0 into VGPRs
    bf16x8 kr0, kr1, vr0, vr1, vr2, vr3;
    {
        const unsigned short* kp = kb + ((size_t)n * HW_ + j0 + stg_row) * 64 + stg_seg * 8;
        kr0 = *(const bf16x8*)kp;
        kr1 = *(const bf16x8*)(kp + 32 * 64);
        const unsigned short* vp = vtb + ((size_t)n * CC + stg_row) * HW_ + j0 + stg_seg * 8;
        vr0 = *(const bf16x8*)vp;
        vr1 = *(const bf16x8*)(vp + (size_t)32 * HW_);
        vr2 = *(const bf16x8*)(vp + (size_t)64 * HW_);
        vr3 = *(const bf16x8*)(vp + (size_t)96 * HW_);
    }

    for (int it = 0; it < iters; ++it, j0 += 64) {
        __syncthreads();   // previous iteration's k/v_lds reads complete
        {
            int r0 = stg_row, r1 = stg_row + 32;
            *(bf16x8*)&k_lds[r0 * 64 + ((stg_seg ^ (r0 & 7)) * 8)] = kr0;
            *(bf16x8*)&k_lds[r1 * 64 + ((stg_seg ^ (r1 & 7)) * 8)] = kr1;
            *(bf16x8*)&v_lds[r0 * 64 + ((stg_seg ^ (r0 & 7)) * 8)] = vr0;
            *(bf16x8*)&v_lds[r1 * 64 + ((stg_seg ^ (r1 & 7)) * 8)] = vr1;
            int r2 = stg_row + 64, r3 = stg_row + 96;
            *(bf16x8*)&v_lds[r2 * 64 + ((stg_seg ^ (r2 & 7)) * 8)] = vr2;
            *(bf16x8*)&v_lds[r3 * 64 + ((stg_seg ^ (r3 & 7)) * 8)] = vr3;
        }
        __syncthreads();

        if (it + 1 < iters) {   // issue next tile's loads; overlap with compute
            const unsigned short* kp = kb + ((size_t)n * HW_ + j0 + 64 + stg_row) * 64 + stg_seg * 8;
            kr0 = *(const bf16x8*)kp;
            kr1 = *(const bf16x8*)(kp + 32 * 64);
            const unsigned short* vp = vtb + ((size_t)n * CC + stg_row) * HW_ + j0 + 64 + stg_seg * 8;
            vr0 = *(const bf16x8*)vp;
            vr1 = *(const bf16x8*)(vp + (size_t)32 * HW_);
            vr2 = *(const bf16x8*)(vp + (size_t)64 * HW_);
            vr3 = *(const bf16x8*)(vp + (size_t)96 * HW_);
        }

        // S^T = K Q^T: 4 tiles along j (16 each), both q-halves per A-read
        f32x4 sa[4], sb[4];
#pragma unroll
        for (int ct = 0; ct < 4; ct++) {
            int jr = ct * 16 + l15;
            bf16x8 ak0 = *(const bf16x8*)&k_lds[jr * 64 + ((quad ^ e7) * 8)];
            bf16x8 ak1 = *(const bf16x8*)&k_lds[jr * 64 + (((4 + quad) ^ e7) * 8)];
            f32x4 za = (f32x4){0.f, 0.f, 0.f, 0.f};
            za = __builtin_amdgcn_mfma_f32_16x16x32_bf16(ak0, bq0a, za, 0, 0, 0);
            za = __builtin_amdgcn_mfma_f32_16x16x32_bf16(ak1, bq1a, za, 0, 0, 0);
            sa[ct] = za;
            f32x4 zb = (f32x4){0.f, 0.f, 0.f, 0.f};
            zb = __builtin_amdgcn_mfma_f32_16x16x32_bf16(ak0, bq0b, zb, 0, 0, 0);
            zb = __builtin_amdgcn_mfma_f32_16x16x32_bf16(ak1, bq1b, zb, 0, 0, 0);
            sb[ct] = zb;
        }

        // ---- half a: P = exp2(S) raw (no max), in-lane l, pack, stage ----
#pragma unroll
        for (int ct = 0; ct < 4; ct++) {
            sa[ct][0] = fast_exp2(sa[ct][0]);
            sa[ct][1] = fast_exp2(sa[ct][1]);
            sa[ct][2] = fast_exp2(sa[ct][2]);
            sa[ct][3] = fast_exp2(sa[ct][3]);
        }
        {   // explicit pairwise tree (no fast-math reassociation available)
            float u0 = sa[0][0] + sa[0][1], u1 = sa[0][2] + sa[0][3];
            float u2 = sa[1][0] + sa[1][1], u3 = sa[1][2] + sa[1][3];
            float u4 = sa[2][0] + sa[2][1], u5 = sa[2][2] + sa[2][3];
            float u6 = sa[3][0] + sa[3][1], u7 = sa[3][2] + sa[3][3];
            float v0 = u0 + u1, v1 = u2 + u3, v2 = u4 + u5, v3 = u6 + u7;
            l_sa += (v0 + v1) + (v2 + v3);
        }
#pragma unroll
        for (int ct = 0; ct < 4; ct++) {
            unsigned int pk01 = cvt_pk_bf16(sa[ct][0], sa[ct][1]);
            unsigned int pk23 = cvt_pk_bf16(sa[ct][2], sa[ct][3]);
            int chunkid = 2 * ct + (quad >> 1);
            int off = l15 * 64 + ((chunkid ^ e7) * 8) + 4 * (quad & 1);
            uint2 tmp;
            tmp.x = pk01;
            tmp.y = pk23;
            *(u16x4*)&p_lds[w * 1024 + off] = __builtin_bit_cast(u16x4, tmp);
        }
        asm volatile("" ::: "memory");   // writes-a before reads-a
        const bf16x8 bp0a = __builtin_bit_cast(bf16x8,
            *(const u16x8*)&p_lds[w * 1024 + l15 * 64 + ((quad ^ e7) * 8)]);
        const bf16x8 bp1a = __builtin_bit_cast(bf16x8,
            *(const u16x8*)&p_lds[w * 1024 + l15 * 64 + (((4 + quad) ^ e7) * 8)]);
        asm volatile("" ::: "memory");   // reads-a before writes-b (buffer reuse)

        // ---- half b ----
#pragma unroll
        for (int ct = 0; ct < 4; ct++) {
            sb[ct][0] = fast_exp2(sb[ct][0]);
            sb[ct][1] = fast_exp2(sb[ct][1]);
            sb[ct][2] = fast_exp2(sb[ct][2]);
            sb[ct][3] = fast_exp2(sb[ct][3]);
        }
        {
            float u0 = sb[0][0] + sb[0][1], u1 = sb[0][2] + sb[0][3];
            float u2 = sb[1][0] + sb[1][1], u3 = sb[1][2] + sb[1][3];
            float u4 = sb[2][0] + sb[2][1], u5 = sb[2][2] + sb[2][3];
            float u6 = sb[3][0] + sb[3][1], u7 = sb[3][2] + sb[3][3];
            float v0 = u0 + u1, v1 = u2 + u3, v2 = u4 + u5, v3 = u6 + u7;
            l_sb += (v0 + v1) + (v2 + v3);
        }
#pragma unroll
        for (int ct = 0; ct < 4; ct++) {
            unsigned int pk01 = cvt_pk_bf16(sb[ct][0], sb[ct][1]);
            unsigned int pk23 = cvt_pk_bf16(sb[ct][2], sb[ct][3]);
            int chunkid = 2 * ct + (quad >> 1);
            int off = l15 * 64 + ((chunkid ^ e7) * 8) + 4 * (quad & 1);
            uint2 tmp;
            tmp.x = pk01;
            tmp.y = pk23;
            *(u16x4*)&p_lds[w * 1024 + off] = __builtin_bit_cast(u16x4, tmp);
        }
        asm volatile("" ::: "memory");   // writes-b before reads-b
        const bf16x8 bp0b = __builtin_bit_cast(bf16x8,
            *(const u16x8*)&p_lds[w * 1024 + l15 * 64 + ((quad ^ e7) * 8)]);
        const bf16x8 bp1b = __builtin_bit_cast(bf16x8,
            *(const u16x8*)&p_lds[w * 1024 + l15 * 64 + (((4 + quad) ^ e7) * 8)]);
        asm volatile("" ::: "memory");   // reads-b before next iter's writes-a

        // O^T += V^T P^T (both halves share each V A-read)
        __builtin_amdgcn_s_setprio(1);
#pragma unroll
        for (int ctv = 0; ctv < 8; ctv++) {
            int cr = ctv * 16 + l15;
            bf16x8 av0 = *(const bf16x8*)&v_lds[cr * 64 + ((quad ^ e7) * 8)];
            bf16x8 av1 = *(const bf16x8*)&v_lds[cr * 64 + (((4 + quad) ^ e7) * 8)];
            acc_oa[ctv] = __builtin_amdgcn_mfma_f32_16x16x32_bf16(av0, bp0a, acc_oa[ctv], 0, 0, 0);
            acc_oa[ctv] = __builtin_amdgcn_mfma_f32_16x16x32_bf16(av1, bp1a, acc_oa[ctv], 0, 0, 0);
            acc_ob[ctv] = __builtin_amdgcn_mfma_f32_16x16x32_bf16(av0, bp0b, acc_ob[ctv], 0, 0, 0);
            acc_ob[ctv] = __builtin_amdgcn_mfma_f32_16x16x32_bf16(av1, bp1b, acc_ob[ctv], 0, 0, 0);
        }
        __builtin_amdgcn_s_setprio(0);
    }

    // epilogue: reduce l across quads (once per kernel, not per iter)
    l_sa += __shfl_xor(l_sa, 16);
    l_sa += __shfl_xor(l_sa, 32);
    l_sb += __shfl_xor(l_sb, 16);
    l_sb += __shfl_xor(l_sb, 32);

    // partials: O^T layout [c][q], q in [0,128) per block
    const size_t cbase = ((size_t)(n * NQT2 + qt) * nch + chunk) * 128;
    const int qla = w * 32 + l15, qlb = qla + 16;
#pragma unroll
    for (int ctv = 0; ctv < 8; ctv++)
#pragma unroll
        for (int r = 0; r < 4; r++) {
            int c = ctv * 16 + 4 * quad + r;
            o_part[(cbase + c) * 128 + qla] = acc_oa[ctv][r];
            o_part[(cbase + c) * 128 + qlb] = acc_ob[ctv][r];
        }
    if (quad == 0) {   // l is quad-uniform per q after the reduce
        size_t lb = ((size_t)(n * NQT2 + qt) * nch + chunk) * 128;
        l_part[lb + qla] = l_sa;
        l_part[lb + qlb] = l_sb;
    }
}

// ---------------------------------------------------------------------------
// Kernel 4: combine nch partials (plain sums — no max tracking), normalize,
// write out[n][c][p] fp32. float4-vectorized over q (4 q per thread).
// Layout: o_part[((nqt*nch+ch)*128 + c)*128 + q], l[(nqt*nch+ch)*128 + q]
// ---------------------------------------------------------------------------
__global__ __launch_bounds__(256) void combine_kernel(
    const float* __restrict__ o_part, const float* __restrict__ lp,
    float* __restrict__ out, int nch) {
    int gid = blockIdx.x * 256 + threadIdx.x;   // covers (nqt, c, q/4)
    int r4 = (gid & 31) * 4;       // q within block, 4 at a time
    int rest = gid >> 5;
    int c = rest & 127;
    int nqt = rest >> 7;           // 0..143 = n*72 + qtp
    int n = nqt / NQT2, qtp = nqt - n * NQT2;

    float4 num = {0.f, 0.f, 0.f, 0.f}, den = {0.f, 0.f, 0.f, 0.f};
    for (int ch = 0; ch < nch; ch++) {
        float4 o = *(const float4*)&o_part[(((size_t)nqt * nch + ch) * 128 + c) * 128 + r4];
        float4 l = *(const float4*)&lp[((size_t)nqt * nch + ch) * 128 + r4];
        num.x += o.x; num.y += o.y; num.z += o.z; num.w += o.w;
        den.x += l.x; den.y += l.y; den.z += l.z; den.w += l.w;
    }
    float4 res;
    res.x = num.x / den.x;
    res.y = num.y / den.y;
    res.z = num.z / den.z;
    res.w = num.w / den.w;
    *(float4*)&out[((size_t)n * CC + c) * HW_ + qtp * 128 + r4] = res;
}

// ---------------------------------------------------------------------------
// Workspace layout (bytes):
//   wh 0 (65536) | wl 65536 (65536) | qb 131072 (2359296) | kb 2490368
//   (2359296) | vtb 4849664 (4718592) | o_part 9568256 (nch*9437184) | l after
// l = nch * 73728 bytes. Ladder: nch 6 (~67 MB, R6-proven) -> 4 -> 2.
// ---------------------------------------------------------------------------
extern "C" void kernel_launch(void* const* d_in, const int* in_sizes, int n_in,
                              void* d_out, int out_size, void* d_ws, size_t ws_size,
                              hipStream_t stream) {
    const float* x  = (const float*)d_in[0];
    const float* w1 = (const float*)d_in[1];
    const float* b1 = (const float*)d_in[2];
    const float* a1 = (const float*)d_in[3];
    const float* w2 = (const float*)d_in[4];
    const float* b2 = (const float*)d_in[5];
    const float* a2 = (const float*)d_in[6];
    const float* wa = (const float*)d_in[7];
    const float* ba = (const float*)d_in[8];
    const float* aa = (const float*)d_in[9];
    float* out = (float*)d_out;

    auto need = [](int nc) -> size_t {
        return 9568256ull + (size_t)nc * 9437184ull + (size_t)nc * 73728ull;
    };
    int nch;
    if (ws_size >= need(6))      nch = 6;    // R6-proven config
    else if (ws_size >= need(4)) nch = 4;
    else                         nch = 2;
    const int chunk_j = HW_ / nch;

    char* ws = (char*)d_ws;
    unsigned short* wh     = (unsigned short*)(ws + 0);
    unsigned short* wl     = (unsigned short*)(ws + 65536);
    unsigned short* qb     = (unsigned short*)(ws + 131072);
    unsigned short* kb     = (unsigned short*)(ws + 2490368);
    unsigned short* vtb    = (unsigned short*)(ws + 4849664);
    float*          o_part = (float*)(ws + 9568256);
    float*          lpart  = (float*)(ws + 9568256 + (size_t)nch * 9437184);

    hipLaunchKernelGGL(prep_w, dim3(128), dim3(256), 0, stream, w1, w2, wa, wh, wl);
    hipLaunchKernelGGL(conv_kernel, dim3(144, 2), dim3(256), 0, stream,
                       x, wh, wl, b1, a1, b2, a2, ba, aa, qb, kb, vtb);
    hipLaunchKernelGGL(attn_kernel, dim3(NQT2, nch, 2), dim3(256), 0, stream,
                       qb, kb, vtb, o_part, lpart, nch, chunk_j);
    hipLaunchKernelGGL(combine_kernel, dim3(2 * NQT2 * 128 * 128 / (256 * 4)), dim3(256), 0, stream,
                       o_part, lpart, out, nch);
}

// Round 16
// 179.971 us; speedup vs baseline: 1.0739x; 1.0189x over previous
//
#include <hip/hip_runtime.h>
#include <cstdint>
#include <cstddef>

// Problem constants (N=2, C=128, Ce=64, H=W=96)
#define HW_ 9216
#define CC 128
#define NQT2 72      // HW/128 q-tiles (attn: 128 q per block)
#define LOG2E 1.44269504088896f

typedef short bf16x8 __attribute__((ext_vector_type(8)));
typedef unsigned short u16x4 __attribute__((ext_vector_type(4)));
typedef unsigned short u16x8 __attribute__((ext_vector_type(8)));
typedef float f32x4 __attribute__((ext_vector_type(4)));

__device__ __forceinline__ unsigned short f2bf(float f) {
    unsigned int u = __builtin_bit_cast(unsigned int, f);
    u += 0x7FFFu + ((u >> 16) & 1u);   // RNE
    return (unsigned short)(u >> 16);
}

__device__ __forceinline__ float bf2f(unsigned short h) {
    return __builtin_bit_cast(float, (unsigned int)h << 16);
}

__device__ __forceinline__ float fast_exp2(float x) {
#if __has_builtin(__builtin_amdgcn_exp2f)
    return __builtin_amdgcn_exp2f(x);   // bare v_exp_f32
#else
    return exp2f(x);
#endif
}

__device__ __forceinline__ unsigned int cvt_pk_bf16(float lo, float hi) {
    unsigned int r;
    asm("v_cvt_pk_bf16_f32 %0, %1, %2" : "=v"(r) : "v"(lo), "v"(hi));
    return r;
}

// ---------------------------------------------------------------------------
// Kernel 1: split weights into bf16 hi/lo pairs, [o][c] layout.
//   o in [0,256): 0..63=w1, 64..127=w2, 128..255=wa.
//   w = hi + lo with |lo| <= 2^-9|w|; bf16x3 MFMA then gives ~2^-18 rel error.
// ---------------------------------------------------------------------------
__global__ __launch_bounds__(256) void prep_w(const float* __restrict__ w1,
                                              const float* __restrict__ w2,
                                              const float* __restrict__ wa,
                                              unsigned short* __restrict__ wh,
                                              unsigned short* __restrict__ wl) {
    int idx = blockIdx.x * 256 + threadIdx.x;   // 32768 total
    int o = idx >> 7, c = idx & 127;
    float v;
    if (o < 64)       v = w1[o * 128 + c];
    else if (o < 128) v = w2[(o - 64) * 128 + c];
    else              v = wa[(o - 128) * 128 + c];
    unsigned short h = f2bf(v);
    unsigned short l = f2bf(v - bf2f(h));
    wh[o * 128 + c] = h;
    wl[o * 128 + c] = l;
}

// ---------------------------------------------------------------------------
// Kernel 2: 1x1 conv + PReLU via bf16x3 MFMA (fp32-accurate split GEMM).
//   R16: p-tile 64 -> 32. Grid 288x2=576 blocks (2.25/CU, tail 1.33x vs R15's
//   2x), LDS 70 -> 37 KB (4 blocks/CU resident -> stage/epilogue overlap).
//   Same MFMA mapping (HW-verified R15) and k-order -> bit-identical output.
//   Block = 4 waves; wave w owns o in [w*64, w*64+64):
//     w0 -> Q (b1,a1, xLOG2E), w1 -> K (b2,a2), w2,w3 -> Vt (ba,aa).
//   A = x-tile (LDS bf16 hi/lo [p][c]); B = wh/wl[o][c] from L2.
//   D: col o = l15, row p = quad*4+r.  acc = ah*bh + ah*bl + al*bh.
// ---------------------------------------------------------------------------
__global__ __launch_bounds__(256, 1) void conv_kernel(
    const float* __restrict__ x,
    const unsigned short* __restrict__ wh, const unsigned short* __restrict__ wl,
    const float* __restrict__ b1, const float* __restrict__ a1,
    const float* __restrict__ b2, const float* __restrict__ a2,
    const float* __restrict__ ba, const float* __restrict__ aa,
    unsigned short* __restrict__ qb, unsigned short* __restrict__ kb,
    unsigned short* __restrict__ vtb) {
    const int ptile = blockIdx.x;   // 288 (32 p each)
    const int n     = blockIdx.y;   // 2
    const int t = threadIdx.x;
    const int w = t >> 6;           // wave = output group
    const int lane = t & 63;
    const int l15 = lane & 15;
    const int quad = lane >> 4;
    const int p0 = ptile * 32;

    __shared__ __align__(16) unsigned short xh[32 * 136];   // [p][c] pad 8, 8.5 KB
    __shared__ __align__(16) unsigned short xl[32 * 136];   // 8.5 KB
    __shared__ __align__(16) unsigned short os[4 * 2560];   // per-wave out tile, 20 KB

    // ---- stage x tile: fp32 -> bf16 hi/lo, transposed to [p][c] ----
    {
        const int cs = t >> 3;          // c start (step 32)
        const int p4 = (t & 7) * 4;     // 4 consecutive p
#pragma unroll
        for (int cc = cs; cc < 128; cc += 32) {
            float4 v = *(const float4*)(x + ((size_t)n * CC + cc) * HW_ + p0 + p4);
            float vv[4] = {v.x, v.y, v.z, v.w};
#pragma unroll
            for (int j = 0; j < 4; j++) {
                unsigned short h = f2bf(vv[j]);
                unsigned short l = f2bf(vv[j] - bf2f(h));
                xh[(p4 + j) * 136 + cc] = h;
                xl[(p4 + j) * 136 + cc] = l;
            }
        }
    }
    __syncthreads();

    // ---- MFMA main loop (96 MFMA/wave) ----
    f32x4 acc[4][2];   // [ot][pt]
#pragma unroll
    for (int ot = 0; ot < 4; ot++)
#pragma unroll
        for (int pt = 0; pt < 2; pt++) acc[ot][pt] = (f32x4){0.f, 0.f, 0.f, 0.f};

#pragma unroll
    for (int k = 0; k < 4; k++) {          // c_off = k*32
        bf16x8 bh[4], bl[4];
#pragma unroll
        for (int ot = 0; ot < 4; ot++) {
            const size_t woff = (size_t)(w * 64 + ot * 16 + l15) * 128 + k * 32 + quad * 8;
            bh[ot] = *(const bf16x8*)(wh + woff);
            bl[ot] = *(const bf16x8*)(wl + woff);
        }
#pragma unroll
        for (int pt = 0; pt < 2; pt++) {
            const int aoff = (pt * 16 + l15) * 136 + k * 32 + quad * 8;
            bf16x8 ah = *(const bf16x8*)&xh[aoff];
            bf16x8 al = *(const bf16x8*)&xl[aoff];
#pragma unroll
            for (int ot = 0; ot < 4; ot++) {
                acc[ot][pt] = __builtin_amdgcn_mfma_f32_16x16x32_bf16(ah, bh[ot], acc[ot][pt], 0, 0, 0);
                acc[ot][pt] = __builtin_amdgcn_mfma_f32_16x16x32_bf16(ah, bl[ot], acc[ot][pt], 0, 0, 0);
                acc[ot][pt] = __builtin_amdgcn_mfma_f32_16x16x32_bf16(al, bh[ot], acc[ot][pt], 0, 0, 0);
            }
        }
    }

    // ---- epilogue: bias + PReLU (+LOG2E for Q), pack to per-wave LDS tile ----
    //   Q/K (w<2): [p][o] rows, stride 72 (32 rows used of the 2560-slot tile)
    //   V (w>=2): [o][p] rows, stride 40 (64 rows)
    const float* bias_p  = (w == 0) ? b1 : (w == 1) ? b2 : ba;
    const float* slope_p = (w == 0) ? a1 : (w == 1) ? a2 : aa;
    const float slope = slope_p[0];
    unsigned short* osw = os + w * 2560;

#pragma unroll
    for (int ot = 0; ot < 4; ot++) {
        const int bidx = (w < 2 ? 0 : (w - 2) * 64) + ot * 16 + l15;
        const float bv = bias_p[bidx];
#pragma unroll
        for (int pt = 0; pt < 2; pt++) {
            unsigned short us[4];
#pragma unroll
            for (int r = 0; r < 4; r++) {
                float y = acc[ot][pt][r] + bv;
                y = (y >= 0.f) ? y : slope * y;
                if (w == 0) y *= LOG2E;   // fold softmax ln->log2 into Q
                us[r] = f2bf(y);
            }
            if (w < 2) {
#pragma unroll
                for (int r = 0; r < 4; r++)
                    osw[(pt * 16 + quad * 4 + r) * 72 + ot * 16 + l15] = us[r];
            } else {
                u16x4 pk = {us[0], us[1], us[2], us[3]};
                *(u16x4*)&osw[(ot * 16 + l15) * 40 + pt * 16 + quad * 4] = pk;
            }
        }
    }
    asm volatile("" ::: "memory");   // os writes before same-wave os reads

    // ---- vectorized store ----
    if (w < 2) {
        // 32 p-rows x 64 o: lane handles (row = lane>>1, half = lane&1), 64B
        const int row = lane >> 1, half = lane & 1;
        const unsigned short* src = osw + row * 72 + half * 32;
        unsigned short* dst = (w == 0 ? qb : kb) + ((size_t)n * HW_ + p0 + row) * 64 + half * 32;
#pragma unroll
        for (int j = 0; j < 4; j++) {
            u16x8 v = *(const u16x8*)(src + j * 8);
            *(u16x8*)(dst + j * 8) = v;
        }
    } else {
        // 64 c-rows x 32 p: lane copies one row, 64B
        const unsigned short* src = osw + lane * 40;
        unsigned short* dst = vtb + ((size_t)(n * CC + (w - 2) * 64 + lane)) * HW_ + p0;
#pragma unroll
        for (int j = 0; j < 4; j++) {
            u16x8 v = *(const u16x8*)(src + j * 8);
            *(u16x8*)(dst + j * 8) = v;
        }
    }
}

// ---------------------------------------------------------------------------
// Kernel 3: flash attention, S^T formulation, 32 q per wave, NO-MAX softmax.
//   EXACT R6 kernel (proven 94-96 us attn, best of 7 structural variants).
//   R16: nch 6 -> 3 (total iter-work nch-invariant; o_part traffic halves).
//   S^T = K·Q^T  (A=K, B=Q)  -> C/D: col = q = lane&15, row = j = quad*4+r
//   P = exp2(S) raw (softmax shift-invariance; S bounded ~40 in log2 domain)
//   l accumulates in-lane; one 2-shfl reduce at epilogue; combine = plain sums
//   P^T staged per-wave in a 1KB buffer reused by both halves (write-a,
//   read-a, write-b, read-b; per-wave DS ops in-order; fences pin order).
//   O^T = V^T·P^T (A=V^T, B=P^T) -> col = q, row = c-local
// Block = 4 waves x 32 q = 128 q. KV chunked over blockIdx.y.
// ---------------------------------------------------------------------------
__global__ __launch_bounds__(256, 2) void attn_kernel(
    const unsigned short* __restrict__ qb, const unsigned short* __restrict__ kb,
    const unsigned short* __restrict__ vtb,
    float* __restrict__ o_part, float* __restrict__ l_part,
    int nch, int chunk_j) {
    const int qt    = blockIdx.x;   // 72
    const int chunk = blockIdx.y;   // nch
    const int n     = blockIdx.z;   // 2
    const int t = threadIdx.x;
    const int w = t >> 6;
    const int lane = t & 63;
    const int l15 = lane & 15;
    const int quad = lane >> 4;
    const int e7 = l15 & 7;

    __shared__ __align__(16) unsigned short k_lds[64 * 64];   // [j][d] swizzled, 8 KB
    __shared__ __align__(16) unsigned short v_lds[128 * 64];  // [c][j] swizzled, 16 KB
    __shared__ __align__(16) unsigned short p_lds[4 * 1024];  // per-wave [q][j], 8 KB

    // Q B-fragments for the two 16-q halves: lane holds q=l15, d = quad*8..
    const int row_ga = qt * 128 + w * 32 + l15;
    const int row_gb = row_ga + 16;
    const bf16x8 bq0a = *(const bf16x8*)(qb + ((size_t)n * HW_ + row_ga) * 64 + quad * 8);
    const bf16x8 bq1a = *(const bf16x8*)(qb + ((size_t)n * HW_ + row_ga) * 64 + 32 + quad * 8);
    const bf16x8 bq0b = *(const bf16x8*)(qb + ((size_t)n * HW_ + row_gb) * 64 + quad * 8);
    const bf16x8 bq1b = *(const bf16x8*)(qb + ((size_t)n * HW_ + row_gb) * 64 + 32 + quad * 8);

    f32x4 acc_oa[8], acc_ob[8];
#pragma unroll
    for (int i = 0; i < 8; i++) {
        acc_oa[i] = (f32x4){0.f, 0.f, 0.f, 0.f};
        acc_ob[i] = (f32x4){0.f, 0.f, 0.f, 0.f};
    }
    float l_sa = 0.f, l_sb = 0.f;   // in-lane partial of l(q); reduced at end

    const int stg_row = t >> 3, stg_seg = t & 7;
    const int iters = chunk_j / 64;
    int j0 = chunk * chunk_j;

    // software pipeline: prefetch tile 0 into VGPRs
    bf16x8 kr0, kr1, vr0, vr1, vr2, vr3;
    {
        const unsigned short* kp = kb + ((size_t)n * HW_ + j0 + stg_row) * 64 + stg_seg * 8;
        kr0 = *(const bf16x8*)kp;
        kr1 = *(const bf16x8*)(kp + 32 * 64);
        const unsigned short* vp = vtb + ((size_t)n * CC + stg_row) * HW_ + j0 + stg_seg * 8;
        vr0 = *(const bf16x8*)vp;
        vr1 = *(const bf16x8*)(vp + (size_t)32 * HW_);
        vr2 = *(const bf16x8*)(vp + (size_t)64 * HW_);
        vr3 = *(const bf16x8*)(vp + (size_t)96 * HW_);
    }

    for (int it = 0; it < iters; ++it, j0 += 64) {
        __syncthreads();   // previous iteration's k/v_lds reads complete
        {
            int r0 = stg_row, r1 = stg_row + 32;
            *(bf16x8*)&k_lds[r0 * 64 + ((stg_seg ^ (r0 & 7)) * 8)] = kr0;
            *(bf16x8*)&k_lds[r1 * 64 + ((stg_seg ^ (r1 & 7)) * 8)] = kr1;
            *(bf16x8*)&v_lds[r0 * 64 + ((stg_seg ^ (r0 & 7)) * 8)] = vr0;
            *(bf16x8*)&v_lds[r1 * 64 + ((stg_seg ^ (r1 & 7)) * 8)] = vr1;
            int r2 = stg_row + 64, r3 = stg_row + 96;
            *(bf16x8*)&v_lds[r2 * 64 + ((stg_seg ^ (r2 & 7)) * 8)] = vr2;
            *(bf16x8*)&v_lds[r3 * 64 + ((stg_seg ^ (r3 & 7)) * 8)] = vr3;
        }
        __syncthreads();

        if (it + 1 < iters) {   // issue next tile's loads; overlap with compute
            const unsigned short* kp = kb + ((size_t)n * HW_ + j0 + 64 + stg_row) * 64 + stg_seg * 8;
            kr0 = *(const bf16x8*)kp;
            kr1 = *(const bf16x8*)(kp + 32 * 64);
            const unsigned short* vp = vtb + ((size_t)n * CC + stg_row) * HW_ + j0 + 64 + stg_seg * 8;
            vr0 = *(const bf16x8*)vp;
            vr1 = *(const bf16x8*)(vp + (size_t)32 * HW_);
            vr2 = *(const bf16x8*)(vp + (size_t)64 * HW_);
            vr3 = *(const bf16x8*)(vp + (size_t)96 * HW_);
        }

        // S^T = K Q^T: 4 tiles along j (16 each), both q-halves per A-read
        f32x4 sa[4], sb[4];
#pragma unroll
        for (int ct = 0; ct < 4; ct++) {
            int jr = ct * 16 + l15;
            bf16x8 ak0 = *(const bf16x8*)&k_lds[jr * 64 + ((quad ^ e7) * 8)];
            bf16x8 ak1 = *(const bf16x8*)&k_lds[jr * 64 + (((4 + quad) ^ e7) * 8)];
            f32x4 za = (f32x4){0.f, 0.f, 0.f, 0.f};
            za = __builtin_amdgcn_mfma_f32_16x16x32_bf16(ak0, bq0a, za, 0, 0, 0);
            za = __builtin_amdgcn_mfma_f32_16x16x32_bf16(ak1, bq1a, za, 0, 0, 0);
            sa[ct] = za;
            f32x4 zb = (f32x4){0.f, 0.f, 0.f, 0.f};
            zb = __builtin_amdgcn_mfma_f32_16x16x32_bf16(ak0, bq0b, zb, 0, 0, 0);
            zb = __builtin_amdgcn_mfma_f32_16x16x32_bf16(ak1, bq1b, zb, 0, 0, 0);
            sb[ct] = zb;
        }

        // ---- half a: P = exp2(S) raw (no max), in-lane l, pack, stage ----
#pragma unroll
        for (int ct = 0; ct < 4; ct++) {
            sa[ct][0] = fast_exp2(sa[ct][0]);
            sa[ct][1] = fast_exp2(sa[ct][1]);
            sa[ct][2] = fast_exp2(sa[ct][2]);
            sa[ct][3] = fast_exp2(sa[ct][3]);
        }
        {   // explicit pairwise tree (no fast-math reassociation available)
            float u0 = sa[0][0] + sa[0][1], u1 = sa[0][2] + sa[0][3];
            float u2 = sa[1][0] + sa[1][1], u3 = sa[1][2] + sa[1][3];
            float u4 = sa[2][0] + sa[2][1], u5 = sa[2][2] + sa[2][3];
            float u6 = sa[3][0] + sa[3][1], u7 = sa[3][2] + sa[3][3];
            float v0 = u0 + u1, v1 = u2 + u3, v2 = u4 + u5, v3 = u6 + u7;
            l_sa += (v0 + v1) + (v2 + v3);
        }
#pragma unroll
        for (int ct = 0; ct < 4; ct++) {
            unsigned int pk01 = cvt_pk_bf16(sa[ct][0], sa[ct][1]);
            unsigned int pk23 = cvt_pk_bf16(sa[ct][2], sa[ct][3]);
            int chunkid = 2 * ct + (quad >> 1);
            int off = l15 * 64 + ((chunkid ^ e7) * 8) + 4 * (quad & 1);
            uint2 tmp;
            tmp.x = pk01;
            tmp.y = pk23;
            *(u16x4*)&p_lds[w * 1024 + off] = __builtin_bit_cast(u16x4, tmp);
        }
        asm volatile("" ::: "memory");   // writes-a before reads-a
        const bf16x8 bp0a = __builtin_bit_cast(bf16x8,
            *(const u16x8*)&p_lds[w * 1024 + l15 * 64 + ((quad ^ e7) * 8)]);
        const bf16x8 bp1a = __builtin_bit_cast(bf16x8,
            *(const u16x8*)&p_lds[w * 1024 + l15 * 64 + (((4 + quad) ^ e7) * 8)]);
        asm volatile("" ::: "memory");   // reads-a before writes-b (buffer reuse)

        // ---- half b ----
#pragma unroll
        for (int ct = 0; ct < 4; ct++) {
            sb[ct][0] = fast_exp2(sb[ct][0]);
            sb[ct][1] = fast_exp2(sb[ct][1]);
            sb[ct][2] = fast_exp2(sb[ct][2]);
            sb[ct][3] = fast_exp2(sb[ct][3]);
        }
        {
            float u0 = sb[0][0] + sb[0][1], u1 = sb[0][2] + sb[0][3];
            float u2 = sb[1][0] + sb[1][1], u3 = sb[1][2] + sb[1][3];
            float u4 = sb[2][0] + sb[2][1], u5 = sb[2][2] + sb[2][3];
            float u6 = sb[3][0] + sb[3][1], u7 = sb[3][2] + sb[3][3];
            float v0 = u0 + u1, v1 = u2 + u3, v2 = u4 + u5, v3 = u6 + u7;
            l_sb += (v0 + v1) + (v2 + v3);
        }
#pragma unroll
        for (int ct = 0; ct < 4; ct++) {
            unsigned int pk01 = cvt_pk_bf16(sb[ct][0], sb[ct][1]);
            unsigned int pk23 = cvt_pk_bf16(sb[ct][2], sb[ct][3]);
            int chunkid = 2 * ct + (quad >> 1);
            int off = l15 * 64 + ((chunkid ^ e7) * 8) + 4 * (quad & 1);
            uint2 tmp;
            tmp.x = pk01;
            tmp.y = pk23;
            *(u16x4*)&p_lds[w * 1024 + off] = __builtin_bit_cast(u16x4, tmp);
        }
        asm volatile("" ::: "memory");   // writes-b before reads-b
        const bf16x8 bp0b = __builtin_bit_cast(bf16x8,
            *(const u16x8*)&p_lds[w * 1024 + l15 * 64 + ((quad ^ e7) * 8)]);
        const bf16x8 bp1b = __builtin_bit_cast(bf16x8,
            *(const u16x8*)&p_lds[w * 1024 + l15 * 64 + (((4 + quad) ^ e7) * 8)]);
        asm volatile("" ::: "memory");   // reads-b before next iter's writes-a

        // O^T += V^T P^T (both halves share each V A-read)
        __builtin_amdgcn_s_setprio(1);
#pragma unroll
        for (int ctv = 0; ctv < 8; ctv++) {
            int cr = ctv * 16 + l15;
            bf16x8 av0 = *(const bf16x8*)&v_lds[cr * 64 + ((quad ^ e7) * 8)];
            bf16x8 av1 = *(const bf16x8*)&v_lds[cr * 64 + (((4 + quad) ^ e7) * 8)];
            acc_oa[ctv] = __builtin_amdgcn_mfma_f32_16x16x32_bf16(av0, bp0a, acc_oa[ctv], 0, 0, 0);
            acc_oa[ctv] = __builtin_amdgcn_mfma_f32_16x16x32_bf16(av1, bp1a, acc_oa[ctv], 0, 0, 0);
            acc_ob[ctv] = __builtin_amdgcn_mfma_f32_16x16x32_bf16(av0, bp0b, acc_ob[ctv], 0, 0, 0);
            acc_ob[ctv] = __builtin_amdgcn_mfma_f32_16x16x32_bf16(av1, bp1b, acc_ob[ctv], 0, 0, 0);
        }
        __builtin_amdgcn_s_setprio(0);
    }

    // epilogue: reduce l across quads (once per kernel, not per iter)
    l_sa += __shfl_xor(l_sa, 16);
    l_sa += __shfl_xor(l_sa, 32);
    l_sb += __shfl_xor(l_sb, 16);
    l_sb += __shfl_xor(l_sb, 32);

    // partials: O^T layout [c][q], q in [0,128) per block
    const size_t cbase = ((size_t)(n * NQT2 + qt) * nch + chunk) * 128;
    const int qla = w * 32 + l15, qlb = qla + 16;
#pragma unroll
    for (int ctv = 0; ctv < 8; ctv++)
#pragma unroll
        for (int r = 0; r < 4; r++) {
            int c = ctv * 16 + 4 * quad + r;
            o_part[(cbase + c) * 128 + qla] = acc_oa[ctv][r];
            o_part[(cbase + c) * 128 + qlb] = acc_ob[ctv][r];
        }
    if (quad == 0) {   // l is quad-uniform per q after the reduce
        size_t lb = ((size_t)(n * NQT2 + qt) * nch + chunk) * 128;
        l_part[lb + qla] = l_sa;
        l_part[lb + qlb] = l_sb;
    }
}

// ---------------------------------------------------------------------------
// Kernel 4: combine nch partials (plain sums — no max tracking), normalize,
// write out[n][c][p] fp32. float4-vectorized over q (4 q per thread).
// Layout: o_part[((nqt*nch+ch)*128 + c)*128 + q], l[(nqt*nch+ch)*128 + q]
// ---------------------------------------------------------------------------
__global__ __launch_bounds__(256) void combine_kernel(
    const float* __restrict__ o_part, const float* __restrict__ lp,
    float* __restrict__ out, int nch) {
    int gid = blockIdx.x * 256 + threadIdx.x;   // covers (nqt, c, q/4)
    int r4 = (gid & 31) * 4;       // q within block, 4 at a time
    int rest = gid >> 5;
    int c = rest & 127;
    int nqt = rest >> 7;           // 0..143 = n*72 + qtp
    int n = nqt / NQT2, qtp = nqt - n * NQT2;

    float4 num = {0.f, 0.f, 0.f, 0.f}, den = {0.f, 0.f, 0.f, 0.f};
    for (int ch = 0; ch < nch; ch++) {
        float4 o = *(const float4*)&o_part[(((size_t)nqt * nch + ch) * 128 + c) * 128 + r4];
        float4 l = *(const float4*)&lp[((size_t)nqt * nch + ch) * 128 + r4];
        num.x += o.x; num.y += o.y; num.z += o.z; num.w += o.w;
        den.x += l.x; den.y += l.y; den.z += l.z; den.w += l.w;
    }
    float4 res;
    res.x = num.x / den.x;
    res.y = num.y / den.y;
    res.z = num.z / den.z;
    res.w = num.w / den.w;
    *(float4*)&out[((size_t)n * CC + c) * HW_ + qtp * 128 + r4] = res;
}

// ---------------------------------------------------------------------------
// Workspace layout (bytes):
//   wh 0 (65536) | wl 65536 (65536) | qb 131072 (2359296) | kb 2490368
//   (2359296) | vtb 4849664 (4718592) | o_part 9568256 (nch*9437184) | l after
// l = nch * 73728 bytes. Ladder: nch 3 (~38 MB; halves combine traffic vs 6,
// attn iter-work and balance nch-invariant) -> 2.
// ---------------------------------------------------------------------------
extern "C" void kernel_launch(void* const* d_in, const int* in_sizes, int n_in,
                              void* d_out, int out_size, void* d_ws, size_t ws_size,
                              hipStream_t stream) {
    const float* x  = (const float*)d_in[0];
    const float* w1 = (const float*)d_in[1];
    const float* b1 = (const float*)d_in[2];
    const float* a1 = (const float*)d_in[3];
    const float* w2 = (const float*)d_in[4];
    const float* b2 = (const float*)d_in[5];
    const float* a2 = (const float*)d_in[6];
    const float* wa = (const float*)d_in[7];
    const float* ba = (const float*)d_in[8];
    const float* aa = (const float*)d_in[9];
    float* out = (float*)d_out;

    auto need = [](int nc) -> size_t {
        return 9568256ull + (size_t)nc * 9437184ull + (size_t)nc * 73728ull;
    };
    int nch;
    if (ws_size >= need(3))      nch = 3;
    else                         nch = 2;
    const int chunk_j = HW_ / nch;

    char* ws = (char*)d_ws;
    unsigned short* wh     = (unsigned short*)(ws + 0);
    unsigned short* wl     = (unsigned short*)(ws + 65536);
    unsigned short* qb     = (unsigned short*)(ws + 131072);
    unsigned short* kb     = (unsigned short*)(ws + 2490368);
    unsigned short* vtb    = (unsigned short*)(ws + 4849664);
    float*          o_part = (float*)(ws + 9568256);
    float*          lpart  = (float*)(ws + 9568256 + (size_t)nch * 9437184);

    hipLaunchKernelGGL(prep_w, dim3(128), dim3(256), 0, stream, w1, w2, wa, wh, wl);
    hipLaunchKernelGGL(conv_kernel, dim3(288, 2), dim3(256), 0, stream,
                       x, wh, wl, b1, a1, b2, a2, ba, aa, qb, kb, vtb);
    hipLaunchKernelGGL(attn_kernel, dim3(NQT2, nch, 2), dim3(256), 0, stream,
                       qb, kb, vtb, o_part, lpart, nch, chunk_j);
    hipLaunchKernelGGL(combine_kernel, dim3(2 * NQT2 * 128 * 128 / (256 * 4)), dim3(256), 0, stream,
                       o_part, lpart, out, nch);
}

// Round 17
// 177.653 us; speedup vs baseline: 1.0879x; 1.0131x over previous
//
#include <hip/hip_runtime.h>
#include <cstdint>
#include <cstddef>

// Problem constants (N=2, C=128, Ce=64, H=W=96)
#define HW_ 9216
#define CC 128
#define NQT2 72      // HW/128 q-tiles (attn: 128 q per block)
#define LOG2E 1.44269504088896f

typedef short bf16x8 __attribute__((ext_vector_type(8)));
typedef unsigned short u16x4 __attribute__((ext_vector_type(4)));
typedef unsigned short u16x8 __attribute__((ext_vector_type(8)));
typedef float f32x4 __attribute__((ext_vector_type(4)));

__device__ __forceinline__ unsigned short f2bf(float f) {
    unsigned int u = __builtin_bit_cast(unsigned int, f);
    u += 0x7FFFu + ((u >> 16) & 1u);   // RNE
    return (unsigned short)(u >> 16);
}

__device__ __forceinline__ float bf2f(unsigned short h) {
    return __builtin_bit_cast(float, (unsigned int)h << 16);
}

__device__ __forceinline__ float fast_exp2(float x) {
#if __has_builtin(__builtin_amdgcn_exp2f)
    return __builtin_amdgcn_exp2f(x);   // bare v_exp_f32
#else
    return exp2f(x);
#endif
}

__device__ __forceinline__ unsigned int cvt_pk_bf16(float lo, float hi) {
    unsigned int r;
    asm("v_cvt_pk_bf16_f32 %0, %1, %2" : "=v"(r) : "v"(lo), "v"(hi));
    return r;
}

// ---------------------------------------------------------------------------
// Kernel 1: 1x1 conv + PReLU via bf16x3 MFMA (fp32-accurate split GEMM).
//   R17: prep_w FOLDED IN — each wave loads its weight fragments as fp32 and
//   splits to bf16 hi/lo in registers (same f2bf RNE sequence as the old
//   prep_w -> conv output bit-identical; removes one kernel launch and the
//   wh/wl workspace round-trip; ~60-70 us of the total is launch/dispatch
//   overhead per the R16 budget).
//   Block = 4 waves; wave w owns o in [w*64, w*64+64):
//     w0 -> Q from w1 (b1,a1, xLOG2E), w1 -> K from w2 (b2,a2),
//     w2 -> Vt rows 0-63 from wa, w3 -> Vt rows 64-127 from wa (ba,aa).
//   A = x-tile (LDS bf16 hi/lo [p][c], 32 p per block); B = split-w in regs.
//   D: col o = l15, row p = quad*4+r (HW-verified R15).
//   acc = ah*bh + ah*bl + al*bh  (3 MFMA per tile-k: residual ~2^-18).
// Grid 288 x 2 = 576 blocks (2.25/CU), LDS 37 KB -> 4 blocks/CU resident.
// ---------------------------------------------------------------------------
__global__ __launch_bounds__(256, 1) void conv_kernel(
    const float* __restrict__ x,
    const float* __restrict__ w1, const float* __restrict__ w2,
    const float* __restrict__ wa,
    const float* __restrict__ b1, const float* __restrict__ a1,
    const float* __restrict__ b2, const float* __restrict__ a2,
    const float* __restrict__ ba, const float* __restrict__ aa,
    unsigned short* __restrict__ qb, unsigned short* __restrict__ kb,
    unsigned short* __restrict__ vtb) {
    const int ptile = blockIdx.x;   // 288 (32 p each)
    const int n     = blockIdx.y;   // 2
    const int t = threadIdx.x;
    const int w = t >> 6;           // wave = output group
    const int lane = t & 63;
    const int l15 = lane & 15;
    const int quad = lane >> 4;
    const int p0 = ptile * 32;

    __shared__ __align__(16) unsigned short xh[32 * 136];   // [p][c] pad 8, 8.5 KB
    __shared__ __align__(16) unsigned short xl[32 * 136];   // 8.5 KB
    __shared__ __align__(16) unsigned short os[4 * 2560];   // per-wave out tile, 20 KB

    // ---- stage x tile: fp32 -> bf16 hi/lo, transposed to [p][c] ----
    {
        const int cs = t >> 3;          // c start (step 32)
        const int p4 = (t & 7) * 4;     // 4 consecutive p
#pragma unroll
        for (int cc = cs; cc < 128; cc += 32) {
            float4 v = *(const float4*)(x + ((size_t)n * CC + cc) * HW_ + p0 + p4);
            float vv[4] = {v.x, v.y, v.z, v.w};
#pragma unroll
            for (int j = 0; j < 4; j++) {
                unsigned short h = f2bf(vv[j]);
                unsigned short l = f2bf(vv[j] - bf2f(h));
                xh[(p4 + j) * 136 + cc] = h;
                xl[(p4 + j) * 136 + cc] = l;
            }
        }
    }
    __syncthreads();

    // wave's weight source (fp32) and row base
    const float* wsrc = (w == 0) ? w1 : (w == 1) ? w2 : wa;
    const int orow0 = (w == 3) ? 64 : 0;

    // ---- MFMA main loop (96 MFMA/wave), weights split in-register ----
    f32x4 acc[4][2];   // [ot][pt]
#pragma unroll
    for (int ot = 0; ot < 4; ot++)
#pragma unroll
        for (int pt = 0; pt < 2; pt++) acc[ot][pt] = (f32x4){0.f, 0.f, 0.f, 0.f};

#pragma unroll
    for (int k = 0; k < 4; k++) {          // c_off = k*32
        bf16x8 bh[4], bl[4];
#pragma unroll
        for (int ot = 0; ot < 4; ot++) {
            const float* wp = wsrc + (size_t)(orow0 + ot * 16 + l15) * 128 + k * 32 + quad * 8;
            float4 w0 = *(const float4*)wp;
            float4 w4 = *(const float4*)(wp + 4);
            float wv[8] = {w0.x, w0.y, w0.z, w0.w, w4.x, w4.y, w4.z, w4.w};
            bf16x8 h8, l8;
#pragma unroll
            for (int j = 0; j < 8; j++) {
                unsigned short h = f2bf(wv[j]);
                unsigned short l = f2bf(wv[j] - bf2f(h));
                h8[j] = (short)h;
                l8[j] = (short)l;
            }
            bh[ot] = h8;
            bl[ot] = l8;
        }
#pragma unroll
        for (int pt = 0; pt < 2; pt++) {
            const int aoff = (pt * 16 + l15) * 136 + k * 32 + quad * 8;
            bf16x8 ah = *(const bf16x8*)&xh[aoff];
            bf16x8 al = *(const bf16x8*)&xl[aoff];
#pragma unroll
            for (int ot = 0; ot < 4; ot++) {
                acc[ot][pt] = __builtin_amdgcn_mfma_f32_16x16x32_bf16(ah, bh[ot], acc[ot][pt], 0, 0, 0);
                acc[ot][pt] = __builtin_amdgcn_mfma_f32_16x16x32_bf16(ah, bl[ot], acc[ot][pt], 0, 0, 0);
                acc[ot][pt] = __builtin_amdgcn_mfma_f32_16x16x32_bf16(al, bh[ot], acc[ot][pt], 0, 0, 0);
            }
        }
    }

    // ---- epilogue: bias + PReLU (+LOG2E for Q), pack to per-wave LDS tile ----
    //   Q/K (w<2): [p][o] rows, stride 72 (32 rows)
    //   V (w>=2): [o][p] rows, stride 40 (64 rows)
    const float* bias_p  = (w == 0) ? b1 : (w == 1) ? b2 : ba;
    const float* slope_p = (w == 0) ? a1 : (w == 1) ? a2 : aa;
    const float slope = slope_p[0];
    unsigned short* osw = os + w * 2560;

#pragma unroll
    for (int ot = 0; ot < 4; ot++) {
        const int bidx = (w < 2 ? 0 : (w - 2) * 64) + ot * 16 + l15;
        const float bv = bias_p[bidx];
#pragma unroll
        for (int pt = 0; pt < 2; pt++) {
            unsigned short us[4];
#pragma unroll
            for (int r = 0; r < 4; r++) {
                float y = acc[ot][pt][r] + bv;
                y = (y >= 0.f) ? y : slope * y;
                if (w == 0) y *= LOG2E;   // fold softmax ln->log2 into Q
                us[r] = f2bf(y);
            }
            if (w < 2) {
#pragma unroll
                for (int r = 0; r < 4; r++)
                    osw[(pt * 16 + quad * 4 + r) * 72 + ot * 16 + l15] = us[r];
            } else {
                u16x4 pk = {us[0], us[1], us[2], us[3]};
                *(u16x4*)&osw[(ot * 16 + l15) * 40 + pt * 16 + quad * 4] = pk;
            }
        }
    }
    asm volatile("" ::: "memory");   // os writes before same-wave os reads

    // ---- vectorized store ----
    if (w < 2) {
        // 32 p-rows x 64 o: lane handles (row = lane>>1, half = lane&1), 64B
        const int row = lane >> 1, half = lane & 1;
        const unsigned short* src = osw + row * 72 + half * 32;
        unsigned short* dst = (w == 0 ? qb : kb) + ((size_t)n * HW_ + p0 + row) * 64 + half * 32;
#pragma unroll
        for (int j = 0; j < 4; j++) {
            u16x8 v = *(const u16x8*)(src + j * 8);
            *(u16x8*)(dst + j * 8) = v;
        }
    } else {
        // 64 c-rows x 32 p: lane copies one row, 64B
        const unsigned short* src = osw + lane * 40;
        unsigned short* dst = vtb + ((size_t)(n * CC + (w - 2) * 64 + lane)) * HW_ + p0;
#pragma unroll
        for (int j = 0; j < 4; j++) {
            u16x8 v = *(const u16x8*)(src + j * 8);
            *(u16x8*)(dst + j * 8) = v;
        }
    }
}

// ---------------------------------------------------------------------------
// Kernel 2: flash attention, S^T formulation, 32 q per wave, NO-MAX softmax.
//   EXACT R6 kernel (proven 94-96 us attn, best of 7 structural variants).
//   nch=3 (R16-proven: halves o_part traffic; iter-work nch-invariant).
//   S^T = K·Q^T  (A=K, B=Q)  -> C/D: col = q = lane&15, row = j = quad*4+r
//   P = exp2(S) raw (softmax shift-invariance; S bounded ~40 in log2 domain)
//   l accumulates in-lane; one 2-shfl reduce at epilogue; combine = plain sums
//   P^T staged per-wave in a 1KB buffer reused by both halves (write-a,
//   read-a, write-b, read-b; per-wave DS ops in-order; fences pin order).
//   O^T = V^T·P^T (A=V^T, B=P^T) -> col = q, row = c-local
// Block = 4 waves x 32 q = 128 q. KV chunked over blockIdx.y.
// ---------------------------------------------------------------------------
__global__ __launch_bounds__(256, 2) void attn_kernel(
    const unsigned short* __restrict__ qb, const unsigned short* __restrict__ kb,
    const unsigned short* __restrict__ vtb,
    float* __restrict__ o_part, float* __restrict__ l_part,
    int nch, int chunk_j) {
    const int qt    = blockIdx.x;   // 72
    const int chunk = blockIdx.y;   // nch
    const int n     = blockIdx.z;   // 2
    const int t = threadIdx.x;
    const int w = t >> 6;
    const int lane = t & 63;
    const int l15 = lane & 15;
    const int quad = lane >> 4;
    const int e7 = l15 & 7;

    __shared__ __align__(16) unsigned short k_lds[64 * 64];   // [j][d] swizzled, 8 KB
    __shared__ __align__(16) unsigned short v_lds[128 * 64];  // [c][j] swizzled, 16 KB
    __shared__ __align__(16) unsigned short p_lds[4 * 1024];  // per-wave [q][j], 8 KB

    // Q B-fragments for the two 16-q halves: lane holds q=l15, d = quad*8..
    const int row_ga = qt * 128 + w * 32 + l15;
    const int row_gb = row_ga + 16;
    const bf16x8 bq0a = *(const bf16x8*)(qb + ((size_t)n * HW_ + row_ga) * 64 + quad * 8);
    const bf16x8 bq1a = *(const bf16x8*)(qb + ((size_t)n * HW_ + row_ga) * 64 + 32 + quad * 8);
    const bf16x8 bq0b = *(const bf16x8*)(qb + ((size_t)n * HW_ + row_gb) * 64 + quad * 8);
    const bf16x8 bq1b = *(const bf16x8*)(qb + ((size_t)n * HW_ + row_gb) * 64 + 32 + quad * 8);

    f32x4 acc_oa[8], acc_ob[8];
#pragma unroll
    for (int i = 0; i < 8; i++) {
        acc_oa[i] = (f32x4){0.f, 0.f, 0.f, 0.f};
        acc_ob[i] = (f32x4){0.f, 0.f, 0.f, 0.f};
    }
    float l_sa = 0.f, l_sb = 0.f;   // in-lane partial of l(q); reduced at end

    const int stg_row = t >> 3, stg_seg = t & 7;
    const int iters = chunk_j / 64;
    int j0 = chunk * chunk_j;

    // software pipeline: prefetch tile 0 into VGPRs
    bf16x8 kr0, kr1, vr0, vr1, vr2, vr3;
    {
        const unsigned short* kp = kb + ((size_t)n * HW_ + j0 + stg_row) * 64 + stg_seg * 8;
        kr0 = *(const bf16x8*)kp;
        kr1 = *(const bf16x8*)(kp + 32 * 64);
        const unsigned short* vp = vtb + ((size_t)n * CC + stg_row) * HW_ + j0 + stg_seg * 8;
        vr0 = *(const bf16x8*)vp;
        vr1 = *(const bf16x8*)(vp + (size_t)32 * HW_);
        vr2 = *(const bf16x8*)(vp + (size_t)64 * HW_);
        vr3 = *(const bf16x8*)(vp + (size_t)96 * HW_);
    }

    for (int it = 0; it < iters; ++it, j0 += 64) {
        __syncthreads();   // previous iteration's k/v_lds reads complete
        {
            int r0 = stg_row, r1 = stg_row + 32;
            *(bf16x8*)&k_lds[r0 * 64 + ((stg_seg ^ (r0 & 7)) * 8)] = kr0;
            *(bf16x8*)&k_lds[r1 * 64 + ((stg_seg ^ (r1 & 7)) * 8)] = kr1;
            *(bf16x8*)&v_lds[r0 * 64 + ((stg_seg ^ (r0 & 7)) * 8)] = vr0;
            *(bf16x8*)&v_lds[r1 * 64 + ((stg_seg ^ (r1 & 7)) * 8)] = vr1;
            int r2 = stg_row + 64, r3 = stg_row + 96;
            *(bf16x8*)&v_lds[r2 * 64 + ((stg_seg ^ (r2 & 7)) * 8)] = vr2;
            *(bf16x8*)&v_lds[r3 * 64 + ((stg_seg ^ (r3 & 7)) * 8)] = vr3;
        }
        __syncthreads();

        if (it + 1 < iters) {   // issue next tile's loads; overlap with compute
            const unsigned short* kp = kb + ((size_t)n * HW_ + j0 + 64 + stg_row) * 64 + stg_seg * 8;
            kr0 = *(const bf16x8*)kp;
            kr1 = *(const bf16x8*)(kp + 32 * 64);
            const unsigned short* vp = vtb + ((size_t)n * CC + stg_row) * HW_ + j0 + 64 + stg_seg * 8;
            vr0 = *(const bf16x8*)vp;
            vr1 = *(const bf16x8*)(vp + (size_t)32 * HW_);
            vr2 = *(const bf16x8*)(vp + (size_t)64 * HW_);
            vr3 = *(const bf16x8*)(vp + (size_t)96 * HW_);
        }

        // S^T = K Q^T: 4 tiles along j (16 each), both q-halves per A-read
        f32x4 sa[4], sb[4];
#pragma unroll
        for (int ct = 0; ct < 4; ct++) {
            int jr = ct * 16 + l15;
            bf16x8 ak0 = *(const bf16x8*)&k_lds[jr * 64 + ((quad ^ e7) * 8)];
            bf16x8 ak1 = *(const bf16x8*)&k_lds[jr * 64 + (((4 + quad) ^ e7) * 8)];
            f32x4 za = (f32x4){0.f, 0.f, 0.f, 0.f};
            za = __builtin_amdgcn_mfma_f32_16x16x32_bf16(ak0, bq0a, za, 0, 0, 0);
            za = __builtin_amdgcn_mfma_f32_16x16x32_bf16(ak1, bq1a, za, 0, 0, 0);
            sa[ct] = za;
            f32x4 zb = (f32x4){0.f, 0.f, 0.f, 0.f};
            zb = __builtin_amdgcn_mfma_f32_16x16x32_bf16(ak0, bq0b, zb, 0, 0, 0);
            zb = __builtin_amdgcn_mfma_f32_16x16x32_bf16(ak1, bq1b, zb, 0, 0, 0);
            sb[ct] = zb;
        }

        // ---- half a: P = exp2(S) raw (no max), in-lane l, pack, stage ----
#pragma unroll
        for (int ct = 0; ct < 4; ct++) {
            sa[ct][0] = fast_exp2(sa[ct][0]);
            sa[ct][1] = fast_exp2(sa[ct][1]);
            sa[ct][2] = fast_exp2(sa[ct][2]);
            sa[ct][3] = fast_exp2(sa[ct][3]);
        }
        {   // explicit pairwise tree (no fast-math reassociation available)
            float u0 = sa[0][0] + sa[0][1], u1 = sa[0][2] + sa[0][3];
            float u2 = sa[1][0] + sa[1][1], u3 = sa[1][2] + sa[1][3];
            float u4 = sa[2][0] + sa[2][1], u5 = sa[2][2] + sa[2][3];
            float u6 = sa[3][0] + sa[3][1], u7 = sa[3][2] + sa[3][3];
            float v0 = u0 + u1, v1 = u2 + u3, v2 = u4 + u5, v3 = u6 + u7;
            l_sa += (v0 + v1) + (v2 + v3);
        }
#pragma unroll
        for (int ct = 0; ct < 4; ct++) {
            unsigned int pk01 = cvt_pk_bf16(sa[ct][0], sa[ct][1]);
            unsigned int pk23 = cvt_pk_bf16(sa[ct][2], sa[ct][3]);
            int chunkid = 2 * ct + (quad >> 1);
            int off = l15 * 64 + ((chunkid ^ e7) * 8) + 4 * (quad & 1);
            uint2 tmp;
            tmp.x = pk01;
            tmp.y = pk23;
            *(u16x4*)&p_lds[w * 1024 + off] = __builtin_bit_cast(u16x4, tmp);
        }
        asm volatile("" ::: "memory");   // writes-a before reads-a
        const bf16x8 bp0a = __builtin_bit_cast(bf16x8,
            *(const u16x8*)&p_lds[w * 1024 + l15 * 64 + ((quad ^ e7) * 8)]);
        const bf16x8 bp1a = __builtin_bit_cast(bf16x8,
            *(const u16x8*)&p_lds[w * 1024 + l15 * 64 + (((4 + quad) ^ e7) * 8)]);
        asm volatile("" ::: "memory");   // reads-a before writes-b (buffer reuse)

        // ---- half b ----
#pragma unroll
        for (int ct = 0; ct < 4; ct++) {
            sb[ct][0] = fast_exp2(sb[ct][0]);
            sb[ct][1] = fast_exp2(sb[ct][1]);
            sb[ct][2] = fast_exp2(sb[ct][2]);
            sb[ct][3] = fast_exp2(sb[ct][3]);
        }
        {
            float u0 = sb[0][0] + sb[0][1], u1 = sb[0][2] + sb[0][3];
            float u2 = sb[1][0] + sb[1][1], u3 = sb[1][2] + sb[1][3];
            float u4 = sb[2][0] + sb[2][1], u5 = sb[2][2] + sb[2][3];
            float u6 = sb[3][0] + sb[3][1], u7 = sb[3][2] + sb[3][3];
            float v0 = u0 + u1, v1 = u2 + u3, v2 = u4 + u5, v3 = u6 + u7;
            l_sb += (v0 + v1) + (v2 + v3);
        }
#pragma unroll
        for (int ct = 0; ct < 4; ct++) {
            unsigned int pk01 = cvt_pk_bf16(sb[ct][0], sb[ct][1]);
            unsigned int pk23 = cvt_pk_bf16(sb[ct][2], sb[ct][3]);
            int chunkid = 2 * ct + (quad >> 1);
            int off = l15 * 64 + ((chunkid ^ e7) * 8) + 4 * (quad & 1);
            uint2 tmp;
            tmp.x = pk01;
            tmp.y = pk23;
            *(u16x4*)&p_lds[w * 1024 + off] = __builtin_bit_cast(u16x4, tmp);
        }
        asm volatile("" ::: "memory");   // writes-b before reads-b
        const bf16x8 bp0b = __builtin_bit_cast(bf16x8,
            *(const u16x8*)&p_lds[w * 1024 + l15 * 64 + ((quad ^ e7) * 8)]);
        const bf16x8 bp1b = __builtin_bit_cast(bf16x8,
            *(const u16x8*)&p_lds[w * 1024 + l15 * 64 + (((4 + quad) ^ e7) * 8)]);
        asm volatile("" ::: "memory");   // reads-b before next iter's writes-a

        // O^T += V^T P^T (both halves share each V A-read)
        __builtin_amdgcn_s_setprio(1);
#pragma unroll
        for (int ctv = 0; ctv < 8; ctv++) {
            int cr = ctv * 16 + l15;
            bf16x8 av0 = *(const bf16x8*)&v_lds[cr * 64 + ((quad ^ e7) * 8)];
            bf16x8 av1 = *(const bf16x8*)&v_lds[cr * 64 + (((4 + quad) ^ e7) * 8)];
            acc_oa[ctv] = __builtin_amdgcn_mfma_f32_16x16x32_bf16(av0, bp0a, acc_oa[ctv], 0, 0, 0);
            acc_oa[ctv] = __builtin_amdgcn_mfma_f32_16x16x32_bf16(av1, bp1a, acc_oa[ctv], 0, 0, 0);
            acc_ob[ctv] = __builtin_amdgcn_mfma_f32_16x16x32_bf16(av0, bp0b, acc_ob[ctv], 0, 0, 0);
            acc_ob[ctv] = __builtin_amdgcn_mfma_f32_16x16x32_bf16(av1, bp1b, acc_ob[ctv], 0, 0, 0);
        }
        __builtin_amdgcn_s_setprio(0);
    }

    // epilogue: reduce l across quads (once per kernel, not per iter)
    l_sa += __shfl_xor(l_sa, 16);
    l_sa += __shfl_xor(l_sa, 32);
    l_sb += __shfl_xor(l_sb, 16);
    l_sb += __shfl_xor(l_sb, 32);

    // partials: O^T layout [c][q], q in [0,128) per block
    const size_t cbase = ((size_t)(n * NQT2 + qt) * nch + chunk) * 128;
    const int qla = w * 32 + l15, qlb = qla + 16;
#pragma unroll
    for (int ctv = 0; ctv < 8; ctv++)
#pragma unroll
        for (int r = 0; r < 4; r++) {
            int c = ctv * 16 + 4 * quad + r;
            o_part[(cbase + c) * 128 + qla] = acc_oa[ctv][r];
            o_part[(cbase + c) * 128 + qlb] = acc_ob[ctv][r];
        }
    if (quad == 0) {   // l is quad-uniform per q after the reduce
        size_t lb = ((size_t)(n * NQT2 + qt) * nch + chunk) * 128;
        l_part[lb + qla] = l_sa;
        l_part[lb + qlb] = l_sb;
    }
}

// ---------------------------------------------------------------------------
// Kernel 3: combine nch partials (plain sums — no max tracking), normalize,
// write out[n][c][p] fp32. float4-vectorized over q (4 q per thread).
// Layout: o_part[((nqt*nch+ch)*128 + c)*128 + q], l[(nqt*nch+ch)*128 + q]
// ---------------------------------------------------------------------------
__global__ __launch_bounds__(256) void combine_kernel(
    const float* __restrict__ o_part, const float* __restrict__ lp,
    float* __restrict__ out, int nch) {
    int gid = blockIdx.x * 256 + threadIdx.x;   // covers (nqt, c, q/4)
    int r4 = (gid & 31) * 4;       // q within block, 4 at a time
    int rest = gid >> 5;
    int c = rest & 127;
    int nqt = rest >> 7;           // 0..143 = n*72 + qtp
    int n = nqt / NQT2, qtp = nqt - n * NQT2;

    float4 num = {0.f, 0.f, 0.f, 0.f}, den = {0.f, 0.f, 0.f, 0.f};
    for (int ch = 0; ch < nch; ch++) {
        float4 o = *(const float4*)&o_part[(((size_t)nqt * nch + ch) * 128 + c) * 128 + r4];
        float4 l = *(const float4*)&lp[((size_t)nqt * nch + ch) * 128 + r4];
        num.x += o.x; num.y += o.y; num.z += o.z; num.w += o.w;
        den.x += l.x; den.y += l.y; den.z += l.z; den.w += l.w;
    }
    float4 res;
    res.x = num.x / den.x;
    res.y = num.y / den.y;
    res.z = num.z / den.z;
    res.w = num.w / den.w;
    *(float4*)&out[((size_t)n * CC + c) * HW_ + qtp * 128 + r4] = res;
}

// ---------------------------------------------------------------------------
// Workspace layout (bytes):
//   qb 0 (2359296) | kb 2359296 (2359296) | vtb 4718592 (4718592)
//   o_part 9437184 (nch*9437184) | l after o_part (nch*73728)
// Ladder: nch 3 (~38 MB; R16-proven) -> 2.
// ---------------------------------------------------------------------------
extern "C" void kernel_launch(void* const* d_in, const int* in_sizes, int n_in,
                              void* d_out, int out_size, void* d_ws, size_t ws_size,
                              hipStream_t stream) {
    const float* x  = (const float*)d_in[0];
    const float* w1 = (const float*)d_in[1];
    const float* b1 = (const float*)d_in[2];
    const float* a1 = (const float*)d_in[3];
    const float* w2 = (const float*)d_in[4];
    const float* b2 = (const float*)d_in[5];
    const float* a2 = (const float*)d_in[6];
    const float* wa = (const float*)d_in[7];
    const float* ba = (const float*)d_in[8];
    const float* aa = (const float*)d_in[9];
    float* out = (float*)d_out;

    auto need = [](int nc) -> size_t {
        return 9437184ull + (size_t)nc * 9437184ull + (size_t)nc * 73728ull;
    };
    int nch;
    if (ws_size >= need(3))      nch = 3;
    else                         nch = 2;
    const int chunk_j = HW_ / nch;

    char* ws = (char*)d_ws;
    unsigned short* qb     = (unsigned short*)(ws + 0);
    unsigned short* kb     = (unsigned short*)(ws + 2359296);
    unsigned short* vtb    = (unsigned short*)(ws + 4718592);
    float*          o_part = (float*)(ws + 9437184);
    float*          lpart  = (float*)(ws + 9437184 + (size_t)nch * 9437184);

    hipLaunchKernelGGL(conv_kernel, dim3(288, 2), dim3(256), 0, stream,
                       x, w1, w2, wa, b1, a1, b2, a2, ba, aa, qb, kb, vtb);
    hipLaunchKernelGGL(attn_kernel, dim3(NQT2, nch, 2), dim3(256), 0, stream,
                       qb, kb, vtb, o_part, lpart, nch, chunk_j);
    hipLaunchKernelGGL(combine_kernel, dim3(2 * NQT2 * 128 * 128 / (256 * 4)), dim3(256), 0, stream,
                       o_part, lpart, out, nch);
}